// Round 14
// baseline (489.345 us; speedup 1.0000x reference)
//
#include <hip/hip_runtime.h>

typedef __attribute__((ext_vector_type(8))) short short8v;
typedef __attribute__((ext_vector_type(8))) unsigned short ushort8v;
typedef __attribute__((ext_vector_type(4))) float float4v;

__device__ __constant__ float c_LO[8] = {
    -0.010597401784997278f, 0.032883011666982945f, 0.030841381835986965f,
    -0.18703481171888114f, -0.02798376941698385f, 0.6308807679295904f,
    0.7148465705525415f, 0.23037781330885523f};
__device__ __constant__ float c_HI[8] = {
    -0.23037781330885523f, 0.7148465705525415f, -0.6308807679295904f,
    -0.02798376941698385f, 0.18703481171888114f, 0.030841381835986965f,
    -0.032883011666982945f, -0.010597401784997278f};

__device__ __forceinline__ unsigned short f2bf(float f) {
    unsigned u = __builtin_bit_cast(unsigned, f);
    unsigned r = u + 0x7fffu + ((u >> 16) & 1u);
    return (unsigned short)(r >> 16);
}
__device__ __forceinline__ float bf2f(unsigned short u) {
    return __builtin_bit_cast(float, (unsigned)u << 16);
}

__device__ __forceinline__ float gelu_fast(float x) {
    float x3 = x * x * x;
    float y = fmaf(0.044715f, x3, x) * 0.7978845608028654f;
    float t = fminf(fmaxf(y * 2.8853900817779268f, -30.f), 30.f);
    float e = exp2f(t);
    return x * e * __builtin_amdgcn_rcpf(e + 1.0f);
}

__device__ __forceinline__ void gload_lds16(const void* g, void* l) {
    __builtin_amdgcn_global_load_lds(g, l, 16, 0, 0);
}

// ---- one DWT level helpers (pywt symmetric) ----
__device__ __forceinline__ void dwt_lvl(const float* __restrict__ in, int n, float* __restrict__ outA,
                                        unsigned short* __restrict__ outD, int m, int lane) {
    for (int j = lane; j < m; j += 64) {
        float a = 0.f, d = 0.f;
#pragma unroll
        for (int i = 0; i < 8; ++i) {
            int p = 2 * j + 7 - i;
            int q = (p < 6) ? (5 - p) : ((p < n + 6) ? (p - 6) : (2 * n + 5 - p));
            float xv = in[q];
            a = fmaf(c_LO[i], xv, a);
            d = fmaf(c_HI[i], xv, d);
        }
        outA[j] = a;
        outD[j] = f2bf(d);
    }
}
__device__ __forceinline__ void dwt_lvl_final(const float* __restrict__ in, int n, unsigned short* __restrict__ outA,
                                              unsigned short* __restrict__ outD, int m, int lane) {
    for (int j = lane; j < m; j += 64) {
        float a = 0.f, d = 0.f;
#pragma unroll
        for (int i = 0; i < 8; ++i) {
            int p = 2 * j + 7 - i;
            int q = (p < 6) ? (5 - p) : ((p < n + 6) ? (p - 6) : (2 * n + 5 - p));
            float xv = in[q];
            a = fmaf(c_LO[i], xv, a);
            d = fmaf(c_HI[i], xv, d);
        }
        outA[j] = f2bf(a);
        outD[j] = f2bf(d);
    }
}

// ---------------- x -> bf16 cast ----------------
__global__ void cast_bf16_kernel(const float* __restrict__ in, unsigned short* __restrict__ out, int n4) {
    int i = blockIdx.x * blockDim.x + threadIdx.x;
    if (i >= n4) return;
    float4 v = ((const float4*)in)[i];
    ushort4 o;
    o.x = f2bf(v.x); o.y = f2bf(v.y); o.z = f2bf(v.z); o.w = f2bf(v.w);
    ((ushort4*)out)[i] = o;
}

// ---------------- CSR build ----------------
__global__ void hist_kernel(const int* __restrict__ rows, int* __restrict__ cnt, int E) {
    int i = blockIdx.x * blockDim.x + threadIdx.x;
    if (i < E) atomicAdd(&cnt[rows[i]], 1);
}

__global__ __launch_bounds__(1024) void scan_kernel(const int* __restrict__ cnt, int* __restrict__ offs,
                                                    int* __restrict__ cursor, int Nrows, int E) {
    __shared__ int part[1024];
    int tid = threadIdx.x;
    const int per = Nrows / 1024;  // 16
    int base = tid * per;
    int local[16];
    int s = 0;
    for (int i = 0; i < per; ++i) { local[i] = s; s += cnt[base + i]; }
    part[tid] = s;
    __syncthreads();
    for (int off = 1; off < 1024; off <<= 1) {
        int v = part[tid];
        int w = (tid >= off) ? part[tid - off] : 0;
        __syncthreads();
        part[tid] = v + w;
        __syncthreads();
    }
    int pre = (tid == 0) ? 0 : part[tid - 1];
    for (int i = 0; i < per; ++i) {
        int o = pre + local[i];
        offs[base + i] = o;
        cursor[base + i] = o;
    }
    if (tid == 0) offs[Nrows] = E;
}

__global__ void scatter_kernel(const int* __restrict__ rows, const int* __restrict__ cols,
                               const float* __restrict__ vals, int* __restrict__ cursor,
                               int* __restrict__ ccol, float* __restrict__ cval, int E) {
    int i = blockIdx.x * blockDim.x + threadIdx.x;
    if (i >= E) return;
    int r = rows[i];
    int p = atomicAdd(&cursor[r], 1);
    ccol[p] = cols[i];
    cval[p] = vals[i];
}

// ---- FUSED: SpMM (CSR, bf16 gather) + 4-level wavedec -> cenc bf16 [N,800] ----
__global__ __launch_bounds__(256) void spmm_wavedec_enc(const unsigned short* __restrict__ xb,
                                                        const int* __restrict__ offs,
                                                        const int* __restrict__ ccol,
                                                        const float* __restrict__ cval,
                                                        unsigned short* __restrict__ cenc) {
    __shared__ float buf0[4][768];
    __shared__ float buf1[4][400];
    const int widx = threadIdx.x >> 6, lane = threadIdx.x & 63;
    const int r = blockIdx.x * 4 + widx;
    float* b0 = buf0[widx];
    float* b1 = buf1[widx];

    int s = offs[r], e = offs[r + 1];
    float acc[12] = {};
    for (int j = s; j < e; ++j) {
        int c = ccol[j];
        float v = cval[j];
        const unsigned short* xr = xb + (size_t)c * 768;
#pragma unroll
        for (int seg = 0; seg < 3; ++seg) {
            ushort4 u = *(const ushort4*)(xr + seg * 256 + lane * 4);
            acc[seg * 4 + 0] = fmaf(v, bf2f(u.x), acc[seg * 4 + 0]);
            acc[seg * 4 + 1] = fmaf(v, bf2f(u.y), acc[seg * 4 + 1]);
            acc[seg * 4 + 2] = fmaf(v, bf2f(u.z), acc[seg * 4 + 2]);
            acc[seg * 4 + 3] = fmaf(v, bf2f(u.w), acc[seg * 4 + 3]);
        }
    }
#pragma unroll
    for (int seg = 0; seg < 3; ++seg) {
        b0[seg * 256 + lane * 4 + 0] = acc[seg * 4 + 0];
        b0[seg * 256 + lane * 4 + 1] = acc[seg * 4 + 1];
        b0[seg * 256 + lane * 4 + 2] = acc[seg * 4 + 2];
        b0[seg * 256 + lane * 4 + 3] = acc[seg * 4 + 3];
    }
    __syncthreads();

    unsigned short* cr = cenc + (size_t)r * 800;
    dwt_lvl(b0, 768, b1, cr + 407, 387, lane);
    __syncthreads();
    dwt_lvl(b1, 387, b0, cr + 210, 197, lane);
    __syncthreads();
    dwt_lvl(b0, 197, b1, cr + 108, 102, lane);
    __syncthreads();
    dwt_lvl_final(b1, 102, cr + 0, cr + 54, 54, lane);
    if (lane < 6) cr[794 + lane] = 0;
}

// ---- FUSED: 4-level wavedec of dec (bf16 in) -> cdec bf16 [N,544] ----
__global__ __launch_bounds__(256) void wavedec_dec(const unsigned short* __restrict__ decb,
                                                   unsigned short* __restrict__ cdec) {
    __shared__ float buf0[4][512];
    __shared__ float buf1[4][272];
    const int widx = threadIdx.x >> 6, lane = threadIdx.x & 63;
    const int r = blockIdx.x * 4 + widx;
    float* b0 = buf0[widx];
    float* b1 = buf1[widx];
    const unsigned short* ip = decb + (size_t)r * 512;
    for (int i = lane; i < 512; i += 64) b0[i] = bf2f(ip[i]);
    __syncthreads();
    unsigned short* cr = cdec + (size_t)r * 544;
    dwt_lvl(b0, 512, b1, cr + 279, 259, lane);
    __syncthreads();
    dwt_lvl(b1, 259, b0, cr + 146, 133, lane);
    __syncthreads();
    dwt_lvl(b0, 133, b1, cr + 76, 70, lane);
    __syncthreads();
    dwt_lvl_final(b1, 70, cr + 0, cr + 38, 38, lane);
    if (lane < 6) cr[538 + lane] = 0;
}

// ---------------- LDS-tiled transpose packs (both sides coalesced) ----------------
struct Bounds { int b[6]; };

// W[b][k][n] f32 -> WT[b][n][k] bf16, k zero-padded to Kpad. grid (ceil(Kpad/64), N/64, NB)
__global__ __launch_bounds__(256) void pack_wT_t(const float* __restrict__ W, unsigned short* __restrict__ WT,
                                                 int K, int N, int Kpad) {
    __shared__ float t[64][65];
    const int b = blockIdx.z;
    const int k0 = blockIdx.x * 64, n0 = blockIdx.y * 64;
    const int tid = threadIdx.x;
#pragma unroll
    for (int i = 0; i < 16; ++i) {
        int idx = tid + i * 256;
        int kk = idx >> 6, nn = idx & 63;
        int k = k0 + kk;
        t[kk][nn] = (k < K) ? W[((size_t)b * K + k) * N + n0 + nn] : 0.f;
    }
    __syncthreads();
#pragma unroll
    for (int i = 0; i < 16; ++i) {
        int idx = tid + i * 256;
        int nn = idx >> 6, kk = idx & 63;
        int k = k0 + kk;
        if (k < Kpad)
            WT[((size_t)b * N + n0 + nn) * Kpad + k] = f2bf(t[kk][nn]);
    }
}

// basis[s][lr][n] stacked-slice -> BT[n][k] bf16. grid (ceil(Kpad/64), N/64)
__global__ __launch_bounds__(256) void pack_basis_t(const float* __restrict__ basis, unsigned short* __restrict__ BT,
                                                    Bounds bd, int brows, int N, int K, int Kpad) {
    __shared__ float t[64][65];
    const int k0 = blockIdx.x * 64, n0 = blockIdx.y * 64;
    const int tid = threadIdx.x;
#pragma unroll
    for (int i = 0; i < 16; ++i) {
        int idx = tid + i * 256;
        int kk = idx >> 6, nn = idx & 63;
        int k = k0 + kk;
        float v = 0.f;
        if (k < K) {
            int s = 0;
#pragma unroll
            for (int u = 1; u < 5; ++u)
                if (k >= bd.b[u]) s = u;
            int lr = k - bd.b[s];
            v = basis[((size_t)s * brows + lr) * N + n0 + nn];
        }
        t[kk][nn] = v;
    }
    __syncthreads();
#pragma unroll
    for (int i = 0; i < 16; ++i) {
        int idx = tid + i * 256;
        int nn = idx >> 6, kk = idx & 63;
        int k = k0 + kk;
        if (k < Kpad)
            BT[(size_t)(n0 + nn) * Kpad + k] = f2bf(t[kk][nn]);
    }
}

// ---------------- bf16 MFMA GEMM, 1D grid + m-major XCD swizzle, f32 out ----------------
__global__ __launch_bounds__(256) void gemm_mfma(const unsigned short* __restrict__ A,
                                                 const unsigned short* __restrict__ BT,
                                                 float* __restrict__ C,
                                                 int M, int N, int K, int lda, int ldb, int ldc, int nx) {
    __shared__ __align__(16) unsigned short As[128 * 32];
    __shared__ __align__(16) unsigned short Bs[128 * 32];
    const int tid = threadIdx.x;
    const int wave = tid >> 6, lane = tid & 63;
    const int nwg = gridDim.x;
    const int logical = (blockIdx.x & 7) * (nwg >> 3) + (blockIdx.x >> 3);
    const int mblk = logical / nx, nblk = logical - mblk * nx;
    const int m0 = mblk * 128, n0 = nblk * 128;
    const int wr = wave >> 1, wc = wave & 1;
    const int frow = lane & 15, fq = lane >> 4;

    const int off0 = tid * 16;
    const int r0 = off0 >> 6, c0 = off0 & 63;
    const int r1 = (off0 + 4096) >> 6, c1 = (off0 + 4096) & 63;
    const char* Ab = (const char*)A;
    const char* Bb = (const char*)BT;
    size_t gA0 = (size_t)(m0 + r0) * lda * 2 + c0;
    size_t gA1 = (size_t)(m0 + r1) * lda * 2 + c1;
    size_t gB0 = (size_t)(n0 + r0) * ldb * 2 + c0;
    size_t gB1 = (size_t)(n0 + r1) * ldb * 2 + c1;
    char* lA0 = (char*)As + wave * 1024;
    char* lB0 = (char*)Bs + wave * 1024;

    const int aoff = (wr * 64 + frow) * 32 + fq * 8;
    const int boff = (wc * 64 + frow) * 32 + fq * 8;

    float4v acc[4][4] = {};
    for (int k0 = 0; k0 < K; k0 += 32) {
        size_t kb2 = (size_t)k0 * 2;
        gload_lds16(Ab + gA0 + kb2, lA0);
        gload_lds16(Ab + gA1 + kb2, lA0 + 4096);
        gload_lds16(Bb + gB0 + kb2, lB0);
        gload_lds16(Bb + gB1 + kb2, lB0 + 4096);
        __syncthreads();
        short8v av[4], bv[4];
#pragma unroll
        for (int i = 0; i < 4; ++i) av[i] = *(const short8v*)(As + aoff + i * 512);
#pragma unroll
        for (int i = 0; i < 4; ++i) bv[i] = *(const short8v*)(Bs + boff + i * 512);
#pragma unroll
        for (int mi = 0; mi < 4; ++mi)
#pragma unroll
            for (int ni = 0; ni < 4; ++ni)
                acc[mi][ni] = __builtin_amdgcn_mfma_f32_16x16x32_bf16(av[mi], bv[ni], acc[mi][ni], 0, 0, 0);
        __syncthreads();
    }
#pragma unroll
    for (int ni = 0; ni < 4; ++ni) {
        int col = n0 + wc * 64 + ni * 16 + frow;
#pragma unroll
        for (int mi = 0; mi < 4; ++mi) {
#pragma unroll
            for (int i = 0; i < 4; ++i) {
                int row = m0 + wr * 64 + mi * 16 + fq * 4 + i;
                C[(size_t)row * ldc + col] = acc[mi][ni][i];
            }
        }
    }
}

// ---- FUSED mu/lv/z GEMM: dual-B (WmuT, WlvT), K=256, N=256; z in epilogue ----
__global__ __launch_bounds__(256) void gemm_muvlz(const unsigned short* __restrict__ A,
                                                  const unsigned short* __restrict__ BmuT,
                                                  const unsigned short* __restrict__ BlvT,
                                                  const float* __restrict__ bmu,
                                                  const float* __restrict__ blv,
                                                  const float* __restrict__ eps,
                                                  float* __restrict__ omu, float* __restrict__ olv,
                                                  unsigned short* __restrict__ zb, int nx) {
    __shared__ __align__(16) unsigned short As[128 * 32];
    __shared__ __align__(16) unsigned short Bmu[128 * 32];
    __shared__ __align__(16) unsigned short Blv[128 * 32];
    const int tid = threadIdx.x;
    const int wave = tid >> 6, lane = tid & 63;
    const int nwg = gridDim.x;
    const int logical = (blockIdx.x & 7) * (nwg >> 3) + (blockIdx.x >> 3);
    const int mblk = logical / nx, nblk = logical - mblk * nx;
    const int m0 = mblk * 128, n0 = nblk * 128;
    const int wr = wave >> 1, wc = wave & 1;
    const int frow = lane & 15, fq = lane >> 4;

    const int off0 = tid * 16;
    const int r0 = off0 >> 6, c0 = off0 & 63;
    const int r1 = (off0 + 4096) >> 6, c1 = (off0 + 4096) & 63;
    const char* Ab = (const char*)A;
    size_t gA0 = (size_t)(m0 + r0) * 512 + c0;   // lda = 256 bf16 = 512 B
    size_t gA1 = (size_t)(m0 + r1) * 512 + c1;
    size_t gB0 = (size_t)(n0 + r0) * 512 + c0;
    size_t gB1 = (size_t)(n0 + r1) * 512 + c1;
    char* lA0 = (char*)As + wave * 1024;
    char* lM0 = (char*)Bmu + wave * 1024;
    char* lV0 = (char*)Blv + wave * 1024;

    const int aoff = (wr * 64 + frow) * 32 + fq * 8;
    const int boff = (wc * 64 + frow) * 32 + fq * 8;

    float4v am[4][4] = {}, al[4][4] = {};
    for (int k0 = 0; k0 < 256; k0 += 32) {
        size_t kb2 = (size_t)k0 * 2;
        gload_lds16(Ab + gA0 + kb2, lA0);
        gload_lds16(Ab + gA1 + kb2, lA0 + 4096);
        gload_lds16((const char*)BmuT + gB0 + kb2, lM0);
        gload_lds16((const char*)BmuT + gB1 + kb2, lM0 + 4096);
        gload_lds16((const char*)BlvT + gB0 + kb2, lV0);
        gload_lds16((const char*)BlvT + gB1 + kb2, lV0 + 4096);
        __syncthreads();
        short8v av[4], bm[4], bl[4];
#pragma unroll
        for (int i = 0; i < 4; ++i) av[i] = *(const short8v*)(As + aoff + i * 512);
#pragma unroll
        for (int i = 0; i < 4; ++i) bm[i] = *(const short8v*)(Bmu + boff + i * 512);
#pragma unroll
        for (int i = 0; i < 4; ++i) bl[i] = *(const short8v*)(Blv + boff + i * 512);
#pragma unroll
        for (int mi = 0; mi < 4; ++mi)
#pragma unroll
            for (int ni = 0; ni < 4; ++ni) {
                am[mi][ni] = __builtin_amdgcn_mfma_f32_16x16x32_bf16(av[mi], bm[ni], am[mi][ni], 0, 0, 0);
                al[mi][ni] = __builtin_amdgcn_mfma_f32_16x16x32_bf16(av[mi], bl[ni], al[mi][ni], 0, 0, 0);
            }
        __syncthreads();
    }
#pragma unroll
    for (int ni = 0; ni < 4; ++ni) {
        int col = n0 + wc * 64 + ni * 16 + frow;
        float bm = bmu[col], bl = blv[col];
#pragma unroll
        for (int mi = 0; mi < 4; ++mi) {
#pragma unroll
            for (int i = 0; i < 4; ++i) {
                int row = m0 + wr * 64 + mi * 16 + fq * 4 + i;
                float mu = am[mi][ni][i] + bm;
                float lv = al[mi][ni][i] + bl;
                float e = eps[(size_t)row * 256 + col];
                omu[(size_t)row * 256 + col] = mu;
                olv[(size_t)row * 256 + col] = lv;
                zb[(size_t)row * 256 + col] = f2bf(mu + e * expf(0.5f * lv));
            }
        }
    }
}

// ---- dendritic enc (K=512): dual-branch, all 20 branches, A re-staged per step ----
__global__ __launch_bounds__(256, 2) void dendritic_full(const unsigned short* __restrict__ A,
                                                         const unsigned short* __restrict__ WT,
                                                         const float* __restrict__ bias,
                                                         unsigned short* __restrict__ out,
                                                         int M, int Nc, int K, int nb, int nx) {
    __shared__ __align__(16) unsigned short As[128 * 64];
    __shared__ __align__(16) unsigned short Bs[2][64 * 64];
    const int tid = threadIdx.x;
    const int wave = tid >> 6;
    const int lane = tid & 63;

    const int nwg = gridDim.x;
    const int logical = (blockIdx.x & 7) * (nwg >> 3) + (blockIdx.x >> 3);
    const int mblk = logical / nx;
    const int nblk = logical - mblk * nx;
    const int n0 = nblk * 64, m0 = mblk * 128;

    const int wr = wave >> 1, wc = wave & 1;
    const int frow = lane & 15, fq = lane >> 4;

    int srA[4], scA[4];
#pragma unroll
    for (int i = 0; i < 4; ++i) {
        int ch = i * 256 + tid;
        srA[i] = ch >> 3;
        scA[i] = ((ch & 7) ^ (srA[i] & 7)) * 16;
    }
    int srB[2], scB[2];
#pragma unroll
    for (int i = 0; i < 2; ++i) {
        int ch = i * 256 + tid;
        srB[i] = ch >> 3;
        scB[i] = ((ch & 7) ^ (srB[i] & 7)) * 16;
    }
    const char* Ab = (const char*)A;
    const size_t K2 = (size_t)K * 2;
    const size_t branchBytes = (size_t)Nc * K2;
    char* lA  = (char*)As + wave * 1024;
    char* lB0 = (char*)&Bs[0][0] + wave * 1024;
    char* lB1 = (char*)&Bs[1][0] + wave * 1024;

    float4v hmn[4][2], hmx[4][2];
#pragma unroll
    for (int mi = 0; mi < 4; ++mi)
#pragma unroll
        for (int ni = 0; ni < 2; ++ni) { hmn[mi][ni] = (float4v)(1e30f); hmx[mi][ni] = (float4v)(-1e30f); }

    const int npair = nb >> 1;
    for (int p = 0; p < npair; ++p) {
        const int b0 = 2 * p, b1 = 2 * p + 1;
        const char* Bb0 = (const char*)WT + (size_t)b0 * branchBytes;
        const char* Bb1 = (const char*)WT + (size_t)b1 * branchBytes;
        float4v ac0[4][2], ac1[4][2];
#pragma unroll
        for (int ni = 0; ni < 2; ++ni) {
            int col = n0 + wc * 32 + ni * 16 + frow;
            float bv0 = bias[(size_t)b0 * Nc + col];
            float bv1 = bias[(size_t)b1 * Nc + col];
#pragma unroll
            for (int mi = 0; mi < 4; ++mi) { ac0[mi][ni] = (float4v)(bv0); ac1[mi][ni] = (float4v)(bv1); }
        }
        for (int k0 = 0; k0 < K; k0 += 64) {
            const size_t kby = (size_t)k0 * 2;
#pragma unroll
            for (int i = 0; i < 4; ++i)
                gload_lds16(Ab + (size_t)(m0 + srA[i]) * K2 + kby + scA[i], lA + i * 4096);
#pragma unroll
            for (int i = 0; i < 2; ++i)
                gload_lds16(Bb0 + (size_t)(n0 + srB[i]) * K2 + kby + scB[i], lB0 + i * 4096);
#pragma unroll
            for (int i = 0; i < 2; ++i)
                gload_lds16(Bb1 + (size_t)(n0 + srB[i]) * K2 + kby + scB[i], lB1 + i * 4096);
            __syncthreads();
#pragma unroll
            for (int kk = 0; kk < 2; ++kk) {
                short8v av[4], bv0[2], bv1[2];
                const int slot = kk * 4 + fq;
#pragma unroll
                for (int mi = 0; mi < 4; ++mi) {
                    int ra = wr * 64 + mi * 16 + frow;
                    av[mi] = *(const short8v*)((const char*)As + ra * 128 + ((slot ^ (ra & 7)) * 16));
                }
#pragma unroll
                for (int ni = 0; ni < 2; ++ni) {
                    int rb = wc * 32 + ni * 16 + frow;
                    int rboff = rb * 128 + ((slot ^ (rb & 7)) * 16);
                    bv0[ni] = *(const short8v*)((const char*)&Bs[0][0] + rboff);
                    bv1[ni] = *(const short8v*)((const char*)&Bs[1][0] + rboff);
                }
#pragma unroll
                for (int mi = 0; mi < 4; ++mi)
#pragma unroll
                    for (int ni = 0; ni < 2; ++ni) {
                        ac0[mi][ni] = __builtin_amdgcn_mfma_f32_16x16x32_bf16(av[mi], bv0[ni], ac0[mi][ni], 0, 0, 0);
                        ac1[mi][ni] = __builtin_amdgcn_mfma_f32_16x16x32_bf16(av[mi], bv1[ni], ac1[mi][ni], 0, 0, 0);
                    }
            }
            __syncthreads();
        }
#pragma unroll
        for (int ni = 0; ni < 2; ++ni)
#pragma unroll
            for (int mi = 0; mi < 4; ++mi)
#pragma unroll
                for (int i = 0; i < 4; ++i) {
                    float mn = fminf(ac0[mi][ni][i], ac1[mi][ni][i]);
                    float mx = fmaxf(ac0[mi][ni][i], ac1[mi][ni][i]);
                    hmn[mi][ni][i] = fminf(hmn[mi][ni][i], mn);
                    hmx[mi][ni][i] = fmaxf(hmx[mi][ni][i], mx);
                }
    }

#pragma unroll
    for (int ni = 0; ni < 2; ++ni) {
        int col = n0 + wc * 32 + ni * 16 + frow;
#pragma unroll
        for (int mi = 0; mi < 4; ++mi) {
#pragma unroll
            for (int i = 0; i < 4; ++i) {
                int row = m0 + wr * 64 + mi * 16 + fq * 4 + i;
                float g = fmaxf(gelu_fast(hmn[mi][ni][i]), gelu_fast(hmx[mi][ni][i]));
                out[(size_t)row * Nc + col] = f2bf(g);
            }
        }
    }
}

// ---- dendritic dec (K=256): A-tile RESIDENT in LDS (64 KB, staged once), B dual streamed ----
// A rows are 512 B = 32 slots of 16B; swizzle: slot' = (slot&~7) | ((slot&7)^(row&7)) (involution).
__global__ __launch_bounds__(256, 2) void dendritic_dec_res(const unsigned short* __restrict__ A,
                                                            const unsigned short* __restrict__ WT,
                                                            const float* __restrict__ bias,
                                                            unsigned short* __restrict__ out,
                                                            int M, int Nc, int nb, int nx) {
    constexpr int K = 256;
    __shared__ __align__(16) unsigned short As[128 * 256];    // 64 KB, resident
    __shared__ __align__(16) unsigned short Bs[2][64 * 64];   // 16 KB
    const int tid = threadIdx.x;
    const int wave = tid >> 6;
    const int lane = tid & 63;

    const int nwg = gridDim.x;
    const int logical = (blockIdx.x & 7) * (nwg >> 3) + (blockIdx.x >> 3);
    const int mblk = logical / nx;
    const int nblk = logical - mblk * nx;
    const int n0 = nblk * 64, m0 = mblk * 128;

    const int wr = wave >> 1, wc = wave & 1;
    const int frow = lane & 15, fq = lane >> 4;

    const char* Ab = (const char*)A;
    const size_t K2 = (size_t)K * 2;  // 512 B per row
    // stage A once: 4096 chunks of 16B; dest linear, source slot pre-swizzled
    for (int i = 0; i < 16; ++i) {
        int ch = i * 256 + tid;
        int row = ch >> 5, slot = ch & 31;
        int sslot = (slot & ~7) | ((slot & 7) ^ (row & 7));
        gload_lds16(Ab + (size_t)(m0 + row) * K2 + sslot * 16, (char*)As + i * 4096 + wave * 1024);
    }

    int srB[2], scB[2];
#pragma unroll
    for (int i = 0; i < 2; ++i) {
        int ch = i * 256 + tid;
        srB[i] = ch >> 3;
        scB[i] = ((ch & 7) ^ (srB[i] & 7)) * 16;
    }
    const size_t branchBytes = (size_t)Nc * K2;
    char* lB0 = (char*)&Bs[0][0] + wave * 1024;
    char* lB1 = (char*)&Bs[1][0] + wave * 1024;

    float4v hmn[4][2], hmx[4][2];
#pragma unroll
    for (int mi = 0; mi < 4; ++mi)
#pragma unroll
        for (int ni = 0; ni < 2; ++ni) { hmn[mi][ni] = (float4v)(1e30f); hmx[mi][ni] = (float4v)(-1e30f); }

    const int npair = nb >> 1;
    for (int p = 0; p < npair; ++p) {
        const int b0 = 2 * p, b1 = 2 * p + 1;
        const char* Bb0 = (const char*)WT + (size_t)b0 * branchBytes;
        const char* Bb1 = (const char*)WT + (size_t)b1 * branchBytes;
        float4v ac0[4][2], ac1[4][2];
#pragma unroll
        for (int ni = 0; ni < 2; ++ni) {
            int col = n0 + wc * 32 + ni * 16 + frow;
            float bv0 = bias[(size_t)b0 * Nc + col];
            float bv1 = bias[(size_t)b1 * Nc + col];
#pragma unroll
            for (int mi = 0; mi < 4; ++mi) { ac0[mi][ni] = (float4v)(bv0); ac1[mi][ni] = (float4v)(bv1); }
        }
        for (int k0 = 0; k0 < K; k0 += 64) {
            const size_t kby = (size_t)k0 * 2;
#pragma unroll
            for (int i = 0; i < 2; ++i)
                gload_lds16(Bb0 + (size_t)(n0 + srB[i]) * K2 + kby + scB[i], lB0 + i * 4096);
#pragma unroll
            for (int i = 0; i < 2; ++i)
                gload_lds16(Bb1 + (size_t)(n0 + srB[i]) * K2 + kby + scB[i], lB1 + i * 4096);
            __syncthreads();  // first iteration also drains A staging
#pragma unroll
            for (int kk = 0; kk < 2; ++kk) {
                short8v av[4], bv0[2], bv1[2];
                const int slot = kk * 4 + fq;      // B slot within 8-slot row
                const int gbase = k0 >> 4;         // A absolute slot base (multiple of 4... {0,4,8,12}*? = k0/16)
#pragma unroll
                for (int mi = 0; mi < 4; ++mi) {
                    int ra = wr * 64 + mi * 16 + frow;
                    int g = (k0 >> 3) + slot;      // absolute 16B-slot in [0,32)
                    int sl = (g & ~7) | ((g & 7) ^ (ra & 7));
                    av[mi] = *(const short8v*)((const char*)As + ra * 512 + sl * 16);
                }
                (void)gbase;
#pragma unroll
                for (int ni = 0; ni < 2; ++ni) {
                    int rb = wc * 32 + ni * 16 + frow;
                    int rboff = rb * 128 + ((slot ^ (rb & 7)) * 16);
                    bv0[ni] = *(const short8v*)((const char*)&Bs[0][0] + rboff);
                    bv1[ni] = *(const short8v*)((const char*)&Bs[1][0] + rboff);
                }
#pragma unroll
                for (int mi = 0; mi < 4; ++mi)
#pragma unroll
                    for (int ni = 0; ni < 2; ++ni) {
                        ac0[mi][ni] = __builtin_amdgcn_mfma_f32_16x16x32_bf16(av[mi], bv0[ni], ac0[mi][ni], 0, 0, 0);
                        ac1[mi][ni] = __builtin_amdgcn_mfma_f32_16x16x32_bf16(av[mi], bv1[ni], ac1[mi][ni], 0, 0, 0);
                    }
            }
            __syncthreads();
        }
#pragma unroll
        for (int ni = 0; ni < 2; ++ni)
#pragma unroll
            for (int mi = 0; mi < 4; ++mi)
#pragma unroll
                for (int i = 0; i < 4; ++i) {
                    float mn = fminf(ac0[mi][ni][i], ac1[mi][ni][i]);
                    float mx = fmaxf(ac0[mi][ni][i], ac1[mi][ni][i]);
                    hmn[mi][ni][i] = fminf(hmn[mi][ni][i], mn);
                    hmx[mi][ni][i] = fmaxf(hmx[mi][ni][i], mx);
                }
    }

#pragma unroll
    for (int ni = 0; ni < 2; ++ni) {
        int col = n0 + wc * 32 + ni * 16 + frow;
#pragma unroll
        for (int mi = 0; mi < 4; ++mi) {
#pragma unroll
            for (int i = 0; i < 4; ++i) {
                int row = m0 + wr * 64 + mi * 16 + fq * 4 + i;
                float g = fmaxf(gelu_fast(hmn[mi][ni][i]), gelu_fast(hmx[mi][ni][i]));
                out[(size_t)row * Nc + col] = f2bf(g);
            }
        }
    }
}

// ---------------- LayerNorm over H=512: f32 in -> bf16 out ----------------
__global__ __launch_bounds__(256) void layernorm_bf16(const float* __restrict__ h,
                                                      unsigned short* __restrict__ o,
                                                      const float* __restrict__ g,
                                                      const float* __restrict__ b) {
    int row = blockIdx.x;
    const float* p = h + (size_t)row * 512;
    int tid = threadIdx.x;
    float v0 = p[tid], v1 = p[tid + 256];
    float s = v0 + v1, sq = v0 * v0 + v1 * v1;
#pragma unroll
    for (int off = 32; off >= 1; off >>= 1) {
        s += __shfl_xor(s, off);
        sq += __shfl_xor(sq, off);
    }
    __shared__ float ls[4], lq[4];
    int wid = tid >> 6, lane = tid & 63;
    if (lane == 0) { ls[wid] = s; lq[wid] = sq; }
    __syncthreads();
    float ts = ls[0] + ls[1] + ls[2] + ls[3];
    float tq = lq[0] + lq[1] + lq[2] + lq[3];
    float mean = ts / 512.f;
    float var = tq / 512.f - mean * mean;
    float inv = rsqrtf(var + 1e-5f);
    unsigned short* op = o + (size_t)row * 512;
    op[tid] = f2bf((v0 - mean) * inv * g[tid] + b[tid]);
    op[tid + 256] = f2bf((v1 - mean) * inv * g[tid + 256] + b[tid + 256]);
}

extern "C" void kernel_launch(void* const* d_in, const int* in_sizes, int n_in,
                              void* d_out, int out_size, void* d_ws, size_t ws_size,
                              hipStream_t stream) {
    const float* x        = (const float*)d_in[0];
    const int*   arows    = (const int*)d_in[1];
    const int*   acols    = (const int*)d_in[2];
    const float* avals    = (const float*)d_in[3];
    const float* basisenc = (const float*)d_in[4];
    const float* ln_g     = (const float*)d_in[5];
    const float* ln_b     = (const float*)d_in[6];
    const float* Wd_enc   = (const float*)d_in[7];
    const float* bd_enc   = (const float*)d_in[8];
    const float* W_mu     = (const float*)d_in[9];
    const float* b_mu     = (const float*)d_in[10];
    const float* W_lv     = (const float*)d_in[11];
    const float* b_lv     = (const float*)d_in[12];
    const float* Wd_dec   = (const float*)d_in[13];
    const float* bd_dec   = (const float*)d_in[14];
    const float* basisdec = (const float*)d_in[15];
    const float* epsin    = (const float*)d_in[16];

    const int N = 16384;
    const int E = in_sizes[1];

    float* ws = (float*)d_ws;
    const size_t A0 = 0;                               // f32 N*768: hF
    const size_t B0 = A0 + (size_t)N * 768;            // u16 N*800: cenc -> [cdec | zb]
    const size_t C0 = B0 + (size_t)N * 400;            // u16: xbf -> [hbf | encb] -> decb
    const size_t F0 = C0 + (size_t)N * 387;            // u16 weights
    const size_t G0 = F0 + 3100672;                    // CSR

    float* hF  = ws + A0;
    unsigned short* cenc = (unsigned short*)(ws + B0);
    unsigned short* cdec = (unsigned short*)(ws + B0);
    unsigned short* zb   = cdec + (size_t)N * 544;
    unsigned short* xbf  = (unsigned short*)(ws + C0);
    unsigned short* hbf  = (unsigned short*)(ws + C0);
    unsigned short* encb = hbf + (size_t)N * 512;
    unsigned short* decb = (unsigned short*)(ws + C0);
    unsigned short* wF = (unsigned short*)(ws + F0);
    unsigned short* BceT   = wF;                       // 512*800
    unsigned short* BcdT   = BceT + 512 * 800;         // 768*544
    unsigned short* WdencT = BcdT + 768 * 544;         // 20*256*512
    unsigned short* WddecT = WdencT + 20 * 256 * 512;  // 20*512*256
    unsigned short* WmuT   = WddecT + 20 * 512 * 256;  // 256*256
    unsigned short* WlvT   = WmuT + 256 * 256;
    int*   csr_cnt  = (int*)(ws + G0);
    int*   csr_offs = csr_cnt + N;
    int*   csr_cur  = csr_offs + N + 1;
    int*   csr_col  = csr_cur + N;
    float* csr_val  = (float*)(csr_col + E);

    float* out_recon = (float*)d_out;
    float* out_mu    = out_recon + (size_t)N * 768;
    float* out_lv    = out_mu + (size_t)N * 256;

    // --- packs + cast (LDS-tiled transposes, both sides coalesced) ---
    {
        Bounds be = {{0, 54, 108, 210, 407, 794}};
        pack_basis_t<<<dim3(13, 8), 256, 0, stream>>>(basisenc, BceT, be, 768, 512, 794, 800);
        Bounds bdd = {{0, 38, 76, 146, 279, 538}};
        pack_basis_t<<<dim3(9, 12), 256, 0, stream>>>(basisdec, BcdT, bdd, 512, 768, 538, 544);
        pack_wT_t<<<dim3(8, 4, 20), 256, 0, stream>>>(Wd_enc, WdencT, 512, 256, 512);
        pack_wT_t<<<dim3(4, 8, 20), 256, 0, stream>>>(Wd_dec, WddecT, 256, 512, 256);
        pack_wT_t<<<dim3(4, 4, 1), 256, 0, stream>>>(W_mu, WmuT, 256, 256, 256);
        pack_wT_t<<<dim3(4, 4, 1), 256, 0, stream>>>(W_lv, WlvT, 256, 256, 256);
        cast_bf16_kernel<<<(N * 768 / 4 + 255) / 256, 256, 0, stream>>>(x, xbf, N * 768 / 4);
    }

    // 1) CSR build + fused SpMM+wavedec-enc -> cenc
    hipMemsetAsync(csr_cnt, 0, N * sizeof(int), stream);
    hist_kernel<<<(E + 255) / 256, 256, 0, stream>>>(arows, csr_cnt, E);
    scan_kernel<<<1, 1024, 0, stream>>>(csr_cnt, csr_offs, csr_cur, N, E);
    scatter_kernel<<<(E + 255) / 256, 256, 0, stream>>>(arows, acols, avals, csr_cur, csr_col, csr_val, E);
    spmm_wavedec_enc<<<N / 4, 256, 0, stream>>>(xbf, csr_offs, csr_col, csr_val, cenc);

    // 2) h = cenc @ BceT^T  [16384,512], K=800.  nwg = 512
    gemm_mfma<<<(512 / 128) * (N / 128), 256, 0, stream>>>(cenc, BceT, hF, N, 512, 800, 800, 800, 512, 512 / 128);

    // 3) layernorm -> bf16
    layernorm_bf16<<<N, 256, 0, stream>>>(hF, hbf, ln_g, ln_b);

    // 4) enc dendritic (K=512): all 20 branches, dual-branch.  nwg = 512
    dendritic_full<<<4 * (N / 128), 256, 0, stream>>>(hbf, WdencT, bd_enc, encb, N, 256, 512, 20, 4);

    // 5) fused mu/lv/z: dual-B GEMM + z epilogue.  nwg = 2*128 = 256
    gemm_muvlz<<<2 * (N / 128), 256, 0, stream>>>(encb, WmuT, WlvT, b_mu, b_lv, epsin, out_mu, out_lv, zb, 2);

    // 6) dec dendritic (K=256): A-resident LDS.  nwg = 8*128 = 1024
    dendritic_dec_res<<<8 * (N / 128), 256, 0, stream>>>(zb, WddecT, bd_dec, decb, N, 512, 20, 8);

    // 7) fused wavedec-dec -> cdec
    wavedec_dec<<<N / 4, 256, 0, stream>>>(decb, cdec);

    // 8) recon = cdec @ BcdT^T [16384,768], K=544.  nwg = 768
    gemm_mfma<<<(768 / 128) * (N / 128), 256, 0, stream>>>(cdec, BcdT, out_recon, N, 768, 544, 544, 544, 768, 768 / 128);

    (void)ws_size; (void)out_size; (void)n_in;
}

// Round 15
// 484.494 us; speedup vs baseline: 1.0100x; 1.0100x over previous
//
#include <hip/hip_runtime.h>

typedef __attribute__((ext_vector_type(8))) short short8v;
typedef __attribute__((ext_vector_type(8))) unsigned short ushort8v;
typedef __attribute__((ext_vector_type(4))) float float4v;

__device__ __constant__ float c_LO[8] = {
    -0.010597401784997278f, 0.032883011666982945f, 0.030841381835986965f,
    -0.18703481171888114f, -0.02798376941698385f, 0.6308807679295904f,
    0.7148465705525415f, 0.23037781330885523f};
__device__ __constant__ float c_HI[8] = {
    -0.23037781330885523f, 0.7148465705525415f, -0.6308807679295904f,
    -0.02798376941698385f, 0.18703481171888114f, 0.030841381835986965f,
    -0.032883011666982945f, -0.010597401784997278f};

__device__ __forceinline__ unsigned short f2bf(float f) {
    unsigned u = __builtin_bit_cast(unsigned, f);
    unsigned r = u + 0x7fffu + ((u >> 16) & 1u);
    return (unsigned short)(r >> 16);
}
__device__ __forceinline__ float bf2f(unsigned short u) {
    return __builtin_bit_cast(float, (unsigned)u << 16);
}

__device__ __forceinline__ float gelu_fast(float x) {
    float x3 = x * x * x;
    float y = fmaf(0.044715f, x3, x) * 0.7978845608028654f;
    float t = fminf(fmaxf(y * 2.8853900817779268f, -30.f), 30.f);
    float e = exp2f(t);
    return x * e * __builtin_amdgcn_rcpf(e + 1.0f);
}

__device__ __forceinline__ void gload_lds16(const void* g, void* l) {
    __builtin_amdgcn_global_load_lds(g, l, 16, 0, 0);
}

// ---- one DWT level helpers (pywt symmetric) ----
__device__ __forceinline__ void dwt_lvl(const float* __restrict__ in, int n, float* __restrict__ outA,
                                        unsigned short* __restrict__ outD, int m, int lane) {
    for (int j = lane; j < m; j += 64) {
        float a = 0.f, d = 0.f;
#pragma unroll
        for (int i = 0; i < 8; ++i) {
            int p = 2 * j + 7 - i;
            int q = (p < 6) ? (5 - p) : ((p < n + 6) ? (p - 6) : (2 * n + 5 - p));
            float xv = in[q];
            a = fmaf(c_LO[i], xv, a);
            d = fmaf(c_HI[i], xv, d);
        }
        outA[j] = a;
        outD[j] = f2bf(d);
    }
}
__device__ __forceinline__ void dwt_lvl_final(const float* __restrict__ in, int n, unsigned short* __restrict__ outA,
                                              unsigned short* __restrict__ outD, int m, int lane) {
    for (int j = lane; j < m; j += 64) {
        float a = 0.f, d = 0.f;
#pragma unroll
        for (int i = 0; i < 8; ++i) {
            int p = 2 * j + 7 - i;
            int q = (p < 6) ? (5 - p) : ((p < n + 6) ? (p - 6) : (2 * n + 5 - p));
            float xv = in[q];
            a = fmaf(c_LO[i], xv, a);
            d = fmaf(c_HI[i], xv, d);
        }
        outA[j] = f2bf(a);
        outD[j] = f2bf(d);
    }
}

// ---------------- x -> bf16 cast ----------------
__global__ void cast_bf16_kernel(const float* __restrict__ in, unsigned short* __restrict__ out, int n4) {
    int i = blockIdx.x * blockDim.x + threadIdx.x;
    if (i >= n4) return;
    float4 v = ((const float4*)in)[i];
    ushort4 o;
    o.x = f2bf(v.x); o.y = f2bf(v.y); o.z = f2bf(v.z); o.w = f2bf(v.w);
    ((ushort4*)out)[i] = o;
}

// ---------------- CSR build ----------------
__global__ void hist_kernel(const int* __restrict__ rows, int* __restrict__ cnt, int E) {
    int i = blockIdx.x * blockDim.x + threadIdx.x;
    if (i < E) atomicAdd(&cnt[rows[i]], 1);
}

__global__ __launch_bounds__(1024) void scan_kernel(const int* __restrict__ cnt, int* __restrict__ offs,
                                                    int* __restrict__ cursor, int Nrows, int E) {
    __shared__ int part[1024];
    int tid = threadIdx.x;
    const int per = Nrows / 1024;  // 16
    int base = tid * per;
    int local[16];
    int s = 0;
    for (int i = 0; i < per; ++i) { local[i] = s; s += cnt[base + i]; }
    part[tid] = s;
    __syncthreads();
    for (int off = 1; off < 1024; off <<= 1) {
        int v = part[tid];
        int w = (tid >= off) ? part[tid - off] : 0;
        __syncthreads();
        part[tid] = v + w;
        __syncthreads();
    }
    int pre = (tid == 0) ? 0 : part[tid - 1];
    for (int i = 0; i < per; ++i) {
        int o = pre + local[i];
        offs[base + i] = o;
        cursor[base + i] = o;
    }
    if (tid == 0) offs[Nrows] = E;
}

__global__ void scatter_kernel(const int* __restrict__ rows, const int* __restrict__ cols,
                               const float* __restrict__ vals, int* __restrict__ cursor,
                               int* __restrict__ ccol, float* __restrict__ cval, int E) {
    int i = blockIdx.x * blockDim.x + threadIdx.x;
    if (i >= E) return;
    int r = rows[i];
    int p = atomicAdd(&cursor[r], 1);
    ccol[p] = cols[i];
    cval[p] = vals[i];
}

// ---- FUSED: SpMM (CSR, bf16 gather) + 4-level wavedec -> cenc bf16 [N,800] ----
__global__ __launch_bounds__(256) void spmm_wavedec_enc(const unsigned short* __restrict__ xb,
                                                        const int* __restrict__ offs,
                                                        const int* __restrict__ ccol,
                                                        const float* __restrict__ cval,
                                                        unsigned short* __restrict__ cenc) {
    __shared__ float buf0[4][768];
    __shared__ float buf1[4][400];
    const int widx = threadIdx.x >> 6, lane = threadIdx.x & 63;
    const int r = blockIdx.x * 4 + widx;
    float* b0 = buf0[widx];
    float* b1 = buf1[widx];

    int s = offs[r], e = offs[r + 1];
    float acc[12] = {};
    for (int j = s; j < e; ++j) {
        int c = ccol[j];
        float v = cval[j];
        const unsigned short* xr = xb + (size_t)c * 768;
#pragma unroll
        for (int seg = 0; seg < 3; ++seg) {
            ushort4 u = *(const ushort4*)(xr + seg * 256 + lane * 4);
            acc[seg * 4 + 0] = fmaf(v, bf2f(u.x), acc[seg * 4 + 0]);
            acc[seg * 4 + 1] = fmaf(v, bf2f(u.y), acc[seg * 4 + 1]);
            acc[seg * 4 + 2] = fmaf(v, bf2f(u.z), acc[seg * 4 + 2]);
            acc[seg * 4 + 3] = fmaf(v, bf2f(u.w), acc[seg * 4 + 3]);
        }
    }
#pragma unroll
    for (int seg = 0; seg < 3; ++seg) {
        b0[seg * 256 + lane * 4 + 0] = acc[seg * 4 + 0];
        b0[seg * 256 + lane * 4 + 1] = acc[seg * 4 + 1];
        b0[seg * 256 + lane * 4 + 2] = acc[seg * 4 + 2];
        b0[seg * 256 + lane * 4 + 3] = acc[seg * 4 + 3];
    }
    __syncthreads();

    unsigned short* cr = cenc + (size_t)r * 800;
    dwt_lvl(b0, 768, b1, cr + 407, 387, lane);
    __syncthreads();
    dwt_lvl(b1, 387, b0, cr + 210, 197, lane);
    __syncthreads();
    dwt_lvl(b0, 197, b1, cr + 108, 102, lane);
    __syncthreads();
    dwt_lvl_final(b1, 102, cr + 0, cr + 54, 54, lane);
    if (lane < 6) cr[794 + lane] = 0;
}

// ---- FUSED: 4-level wavedec of dec (bf16 in) -> cdec bf16 [N,544] ----
__global__ __launch_bounds__(256) void wavedec_dec(const unsigned short* __restrict__ decb,
                                                   unsigned short* __restrict__ cdec) {
    __shared__ float buf0[4][512];
    __shared__ float buf1[4][272];
    const int widx = threadIdx.x >> 6, lane = threadIdx.x & 63;
    const int r = blockIdx.x * 4 + widx;
    float* b0 = buf0[widx];
    float* b1 = buf1[widx];
    const unsigned short* ip = decb + (size_t)r * 512;
    for (int i = lane; i < 512; i += 64) b0[i] = bf2f(ip[i]);
    __syncthreads();
    unsigned short* cr = cdec + (size_t)r * 544;
    dwt_lvl(b0, 512, b1, cr + 279, 259, lane);
    __syncthreads();
    dwt_lvl(b1, 259, b0, cr + 146, 133, lane);
    __syncthreads();
    dwt_lvl(b0, 133, b1, cr + 76, 70, lane);
    __syncthreads();
    dwt_lvl_final(b1, 70, cr + 0, cr + 38, 38, lane);
    if (lane < 6) cr[538 + lane] = 0;
}

// ---------------- LDS-tiled transpose packs (both sides coalesced) ----------------
struct Bounds { int b[6]; };

__global__ __launch_bounds__(256) void pack_wT_t(const float* __restrict__ W, unsigned short* __restrict__ WT,
                                                 int K, int N, int Kpad) {
    __shared__ float t[64][65];
    const int b = blockIdx.z;
    const int k0 = blockIdx.x * 64, n0 = blockIdx.y * 64;
    const int tid = threadIdx.x;
#pragma unroll
    for (int i = 0; i < 16; ++i) {
        int idx = tid + i * 256;
        int kk = idx >> 6, nn = idx & 63;
        int k = k0 + kk;
        t[kk][nn] = (k < K) ? W[((size_t)b * K + k) * N + n0 + nn] : 0.f;
    }
    __syncthreads();
#pragma unroll
    for (int i = 0; i < 16; ++i) {
        int idx = tid + i * 256;
        int nn = idx >> 6, kk = idx & 63;
        int k = k0 + kk;
        if (k < Kpad)
            WT[((size_t)b * N + n0 + nn) * Kpad + k] = f2bf(t[kk][nn]);
    }
}

__global__ __launch_bounds__(256) void pack_basis_t(const float* __restrict__ basis, unsigned short* __restrict__ BT,
                                                    Bounds bd, int brows, int N, int K, int Kpad) {
    __shared__ float t[64][65];
    const int k0 = blockIdx.x * 64, n0 = blockIdx.y * 64;
    const int tid = threadIdx.x;
#pragma unroll
    for (int i = 0; i < 16; ++i) {
        int idx = tid + i * 256;
        int kk = idx >> 6, nn = idx & 63;
        int k = k0 + kk;
        float v = 0.f;
        if (k < K) {
            int s = 0;
#pragma unroll
            for (int u = 1; u < 5; ++u)
                if (k >= bd.b[u]) s = u;
            int lr = k - bd.b[s];
            v = basis[((size_t)s * brows + lr) * N + n0 + nn];
        }
        t[kk][nn] = v;
    }
    __syncthreads();
#pragma unroll
    for (int i = 0; i < 16; ++i) {
        int idx = tid + i * 256;
        int nn = idx >> 6, kk = idx & 63;
        int k = k0 + kk;
        if (k < Kpad)
            BT[(size_t)(n0 + nn) * Kpad + k] = f2bf(t[kk][nn]);
    }
}

// ---------------- bf16 MFMA GEMM, 1D grid + m-major XCD swizzle ----------------
// MODE 0: f32 out. MODE 2: mu/lv split epilogue (cols<256 -> Cv+bias, else Cv2+bias2; both ld 256).
template <int MODE>
__global__ __launch_bounds__(256) void gemm_mfma(const unsigned short* __restrict__ A,
                                                 const unsigned short* __restrict__ BT,
                                                 const float* __restrict__ bias,
                                                 const float* __restrict__ bias2,
                                                 void* __restrict__ Cv, void* __restrict__ Cv2,
                                                 int M, int N, int K, int lda, int ldb, int ldc, int nx) {
    __shared__ __align__(16) unsigned short As[128 * 32];
    __shared__ __align__(16) unsigned short Bs[128 * 32];
    const int tid = threadIdx.x;
    const int wave = tid >> 6, lane = tid & 63;
    const int nwg = gridDim.x;
    const int logical = (blockIdx.x & 7) * (nwg >> 3) + (blockIdx.x >> 3);
    const int mblk = logical / nx, nblk = logical - mblk * nx;
    const int m0 = mblk * 128, n0 = nblk * 128;
    const int wr = wave >> 1, wc = wave & 1;
    const int frow = lane & 15, fq = lane >> 4;

    const int off0 = tid * 16;
    const int r0 = off0 >> 6, c0 = off0 & 63;
    const int r1 = (off0 + 4096) >> 6, c1 = (off0 + 4096) & 63;
    const char* Ab = (const char*)A;
    const char* Bb = (const char*)BT;
    size_t gA0 = (size_t)(m0 + r0) * lda * 2 + c0;
    size_t gA1 = (size_t)(m0 + r1) * lda * 2 + c1;
    size_t gB0 = (size_t)(n0 + r0) * ldb * 2 + c0;
    size_t gB1 = (size_t)(n0 + r1) * ldb * 2 + c1;
    char* lA0 = (char*)As + wave * 1024;
    char* lB0 = (char*)Bs + wave * 1024;

    const int aoff = (wr * 64 + frow) * 32 + fq * 8;
    const int boff = (wc * 64 + frow) * 32 + fq * 8;

    float4v acc[4][4] = {};
    for (int k0 = 0; k0 < K; k0 += 32) {
        size_t kb2 = (size_t)k0 * 2;
        gload_lds16(Ab + gA0 + kb2, lA0);
        gload_lds16(Ab + gA1 + kb2, lA0 + 4096);
        gload_lds16(Bb + gB0 + kb2, lB0);
        gload_lds16(Bb + gB1 + kb2, lB0 + 4096);
        __syncthreads();
        short8v av[4], bv[4];
#pragma unroll
        for (int i = 0; i < 4; ++i) av[i] = *(const short8v*)(As + aoff + i * 512);
#pragma unroll
        for (int i = 0; i < 4; ++i) bv[i] = *(const short8v*)(Bs + boff + i * 512);
#pragma unroll
        for (int mi = 0; mi < 4; ++mi)
#pragma unroll
            for (int ni = 0; ni < 4; ++ni)
                acc[mi][ni] = __builtin_amdgcn_mfma_f32_16x16x32_bf16(av[mi], bv[ni], acc[mi][ni], 0, 0, 0);
        __syncthreads();
    }
#pragma unroll
    for (int ni = 0; ni < 4; ++ni) {
        int col = n0 + wc * 64 + ni * 16 + frow;
        float bval;
        float* dst;
        int coll;
        if (MODE == 2) {
            bool isMu = col < 256;
            coll = col & 255;
            bval = isMu ? bias[coll] : bias2[coll];
            dst = (float*)(isMu ? Cv : Cv2);
        } else {
            coll = col;
            bval = 0.f;
            dst = (float*)Cv;
        }
#pragma unroll
        for (int mi = 0; mi < 4; ++mi) {
#pragma unroll
            for (int i = 0; i < 4; ++i) {
                int row = m0 + wr * 64 + mi * 16 + fq * 4 + i;
                float v = acc[mi][ni][i] + bval;
                if (MODE == 2)
                    dst[(size_t)row * 256 + coll] = v;
                else
                    dst[(size_t)row * ldc + coll] = v;
            }
        }
    }
}

// ---------------- z = mu + eps * exp(0.5*logvar)  -> bf16 ----------------
__global__ void z_kernel(const float* __restrict__ mu, const float* __restrict__ lv,
                         const float* __restrict__ eps, unsigned short* __restrict__ z, int n4) {
    int i = blockIdx.x * blockDim.x + threadIdx.x;
    if (i >= n4) return;
    float4 m = ((const float4*)mu)[i];
    float4 l = ((const float4*)lv)[i];
    float4 e = ((const float4*)eps)[i];
    ushort4 o;
    o.x = f2bf(m.x + e.x * expf(0.5f * l.x));
    o.y = f2bf(m.y + e.y * expf(0.5f * l.y));
    o.z = f2bf(m.z + e.z * expf(0.5f * l.z));
    o.w = f2bf(m.w + e.w * expf(0.5f * l.w));
    ((ushort4*)z)[i] = o;
}

// ---- dendritic enc (K=512): dual-branch, all 20 branches, A re-staged per step ----
__global__ __launch_bounds__(256, 2) void dendritic_full(const unsigned short* __restrict__ A,
                                                         const unsigned short* __restrict__ WT,
                                                         const float* __restrict__ bias,
                                                         unsigned short* __restrict__ out,
                                                         int M, int Nc, int K, int nb, int nx) {
    __shared__ __align__(16) unsigned short As[128 * 64];
    __shared__ __align__(16) unsigned short Bs[2][64 * 64];
    const int tid = threadIdx.x;
    const int wave = tid >> 6;
    const int lane = tid & 63;

    const int nwg = gridDim.x;
    const int logical = (blockIdx.x & 7) * (nwg >> 3) + (blockIdx.x >> 3);
    const int mblk = logical / nx;
    const int nblk = logical - mblk * nx;
    const int n0 = nblk * 64, m0 = mblk * 128;

    const int wr = wave >> 1, wc = wave & 1;
    const int frow = lane & 15, fq = lane >> 4;

    int srA[4], scA[4];
#pragma unroll
    for (int i = 0; i < 4; ++i) {
        int ch = i * 256 + tid;
        srA[i] = ch >> 3;
        scA[i] = ((ch & 7) ^ (srA[i] & 7)) * 16;
    }
    int srB[2], scB[2];
#pragma unroll
    for (int i = 0; i < 2; ++i) {
        int ch = i * 256 + tid;
        srB[i] = ch >> 3;
        scB[i] = ((ch & 7) ^ (srB[i] & 7)) * 16;
    }
    const char* Ab = (const char*)A;
    const size_t K2 = (size_t)K * 2;
    const size_t branchBytes = (size_t)Nc * K2;
    char* lA  = (char*)As + wave * 1024;
    char* lB0 = (char*)&Bs[0][0] + wave * 1024;
    char* lB1 = (char*)&Bs[1][0] + wave * 1024;

    float4v hmn[4][2], hmx[4][2];
#pragma unroll
    for (int mi = 0; mi < 4; ++mi)
#pragma unroll
        for (int ni = 0; ni < 2; ++ni) { hmn[mi][ni] = (float4v)(1e30f); hmx[mi][ni] = (float4v)(-1e30f); }

    const int npair = nb >> 1;
    for (int p = 0; p < npair; ++p) {
        const int b0 = 2 * p, b1 = 2 * p + 1;
        const char* Bb0 = (const char*)WT + (size_t)b0 * branchBytes;
        const char* Bb1 = (const char*)WT + (size_t)b1 * branchBytes;
        float4v ac0[4][2], ac1[4][2];
#pragma unroll
        for (int ni = 0; ni < 2; ++ni) {
            int col = n0 + wc * 32 + ni * 16 + frow;
            float bv0 = bias[(size_t)b0 * Nc + col];
            float bv1 = bias[(size_t)b1 * Nc + col];
#pragma unroll
            for (int mi = 0; mi < 4; ++mi) { ac0[mi][ni] = (float4v)(bv0); ac1[mi][ni] = (float4v)(bv1); }
        }
        for (int k0 = 0; k0 < K; k0 += 64) {
            const size_t kby = (size_t)k0 * 2;
#pragma unroll
            for (int i = 0; i < 4; ++i)
                gload_lds16(Ab + (size_t)(m0 + srA[i]) * K2 + kby + scA[i], lA + i * 4096);
#pragma unroll
            for (int i = 0; i < 2; ++i)
                gload_lds16(Bb0 + (size_t)(n0 + srB[i]) * K2 + kby + scB[i], lB0 + i * 4096);
#pragma unroll
            for (int i = 0; i < 2; ++i)
                gload_lds16(Bb1 + (size_t)(n0 + srB[i]) * K2 + kby + scB[i], lB1 + i * 4096);
            __syncthreads();
#pragma unroll
            for (int kk = 0; kk < 2; ++kk) {
                short8v av[4], bv0[2], bv1[2];
                const int slot = kk * 4 + fq;
#pragma unroll
                for (int mi = 0; mi < 4; ++mi) {
                    int ra = wr * 64 + mi * 16 + frow;
                    av[mi] = *(const short8v*)((const char*)As + ra * 128 + ((slot ^ (ra & 7)) * 16));
                }
#pragma unroll
                for (int ni = 0; ni < 2; ++ni) {
                    int rb = wc * 32 + ni * 16 + frow;
                    int rboff = rb * 128 + ((slot ^ (rb & 7)) * 16);
                    bv0[ni] = *(const short8v*)((const char*)&Bs[0][0] + rboff);
                    bv1[ni] = *(const short8v*)((const char*)&Bs[1][0] + rboff);
                }
#pragma unroll
                for (int mi = 0; mi < 4; ++mi)
#pragma unroll
                    for (int ni = 0; ni < 2; ++ni) {
                        ac0[mi][ni] = __builtin_amdgcn_mfma_f32_16x16x32_bf16(av[mi], bv0[ni], ac0[mi][ni], 0, 0, 0);
                        ac1[mi][ni] = __builtin_amdgcn_mfma_f32_16x16x32_bf16(av[mi], bv1[ni], ac1[mi][ni], 0, 0, 0);
                    }
            }
            __syncthreads();
        }
#pragma unroll
        for (int ni = 0; ni < 2; ++ni)
#pragma unroll
            for (int mi = 0; mi < 4; ++mi)
#pragma unroll
                for (int i = 0; i < 4; ++i) {
                    float mn = fminf(ac0[mi][ni][i], ac1[mi][ni][i]);
                    float mx = fmaxf(ac0[mi][ni][i], ac1[mi][ni][i]);
                    hmn[mi][ni][i] = fminf(hmn[mi][ni][i], mn);
                    hmx[mi][ni][i] = fmaxf(hmx[mi][ni][i], mx);
                }
    }

#pragma unroll
    for (int ni = 0; ni < 2; ++ni) {
        int col = n0 + wc * 32 + ni * 16 + frow;
#pragma unroll
        for (int mi = 0; mi < 4; ++mi) {
#pragma unroll
            for (int i = 0; i < 4; ++i) {
                int row = m0 + wr * 64 + mi * 16 + fq * 4 + i;
                float g = fmaxf(gelu_fast(hmn[mi][ni][i]), gelu_fast(hmx[mi][ni][i]));
                out[(size_t)row * Nc + col] = f2bf(g);
            }
        }
    }
}

// ---- dendritic dec (K=256): A-tile RESIDENT in LDS (64 KB, staged once), B dual streamed ----
__global__ __launch_bounds__(256, 2) void dendritic_dec_res(const unsigned short* __restrict__ A,
                                                            const unsigned short* __restrict__ WT,
                                                            const float* __restrict__ bias,
                                                            unsigned short* __restrict__ out,
                                                            int M, int Nc, int nb, int nx) {
    constexpr int K = 256;
    __shared__ __align__(16) unsigned short As[128 * 256];    // 64 KB, resident
    __shared__ __align__(16) unsigned short Bs[2][64 * 64];   // 16 KB
    const int tid = threadIdx.x;
    const int wave = tid >> 6;
    const int lane = tid & 63;

    const int nwg = gridDim.x;
    const int logical = (blockIdx.x & 7) * (nwg >> 3) + (blockIdx.x >> 3);
    const int mblk = logical / nx;
    const int nblk = logical - mblk * nx;
    const int n0 = nblk * 64, m0 = mblk * 128;

    const int wr = wave >> 1, wc = wave & 1;
    const int frow = lane & 15, fq = lane >> 4;

    const char* Ab = (const char*)A;
    const size_t K2 = (size_t)K * 2;
    for (int i = 0; i < 16; ++i) {
        int ch = i * 256 + tid;
        int row = ch >> 5, slot = ch & 31;
        int sslot = (slot & ~7) | ((slot & 7) ^ (row & 7));
        gload_lds16(Ab + (size_t)(m0 + row) * K2 + sslot * 16, (char*)As + i * 4096 + wave * 1024);
    }

    int srB[2], scB[2];
#pragma unroll
    for (int i = 0; i < 2; ++i) {
        int ch = i * 256 + tid;
        srB[i] = ch >> 3;
        scB[i] = ((ch & 7) ^ (srB[i] & 7)) * 16;
    }
    const size_t branchBytes = (size_t)Nc * K2;
    char* lB0 = (char*)&Bs[0][0] + wave * 1024;
    char* lB1 = (char*)&Bs[1][0] + wave * 1024;

    float4v hmn[4][2], hmx[4][2];
#pragma unroll
    for (int mi = 0; mi < 4; ++mi)
#pragma unroll
        for (int ni = 0; ni < 2; ++ni) { hmn[mi][ni] = (float4v)(1e30f); hmx[mi][ni] = (float4v)(-1e30f); }

    const int npair = nb >> 1;
    for (int p = 0; p < npair; ++p) {
        const int b0 = 2 * p, b1 = 2 * p + 1;
        const char* Bb0 = (const char*)WT + (size_t)b0 * branchBytes;
        const char* Bb1 = (const char*)WT + (size_t)b1 * branchBytes;
        float4v ac0[4][2], ac1[4][2];
#pragma unroll
        for (int ni = 0; ni < 2; ++ni) {
            int col = n0 + wc * 32 + ni * 16 + frow;
            float bv0 = bias[(size_t)b0 * Nc + col];
            float bv1 = bias[(size_t)b1 * Nc + col];
#pragma unroll
            for (int mi = 0; mi < 4; ++mi) { ac0[mi][ni] = (float4v)(bv0); ac1[mi][ni] = (float4v)(bv1); }
        }
        for (int k0 = 0; k0 < K; k0 += 64) {
            const size_t kby = (size_t)k0 * 2;
#pragma unroll
            for (int i = 0; i < 2; ++i)
                gload_lds16(Bb0 + (size_t)(n0 + srB[i]) * K2 + kby + scB[i], lB0 + i * 4096);
#pragma unroll
            for (int i = 0; i < 2; ++i)
                gload_lds16(Bb1 + (size_t)(n0 + srB[i]) * K2 + kby + scB[i], lB1 + i * 4096);
            __syncthreads();
#pragma unroll
            for (int kk = 0; kk < 2; ++kk) {
                short8v av[4], bv0[2], bv1[2];
                const int slot = kk * 4 + fq;
#pragma unroll
                for (int mi = 0; mi < 4; ++mi) {
                    int ra = wr * 64 + mi * 16 + frow;
                    int g = (k0 >> 3) + slot;
                    int sl = (g & ~7) | ((g & 7) ^ (ra & 7));
                    av[mi] = *(const short8v*)((const char*)As + ra * 512 + sl * 16);
                }
#pragma unroll
                for (int ni = 0; ni < 2; ++ni) {
                    int rb = wc * 32 + ni * 16 + frow;
                    int rboff = rb * 128 + ((slot ^ (rb & 7)) * 16);
                    bv0[ni] = *(const short8v*)((const char*)&Bs[0][0] + rboff);
                    bv1[ni] = *(const short8v*)((const char*)&Bs[1][0] + rboff);
                }
#pragma unroll
                for (int mi = 0; mi < 4; ++mi)
#pragma unroll
                    for (int ni = 0; ni < 2; ++ni) {
                        ac0[mi][ni] = __builtin_amdgcn_mfma_f32_16x16x32_bf16(av[mi], bv0[ni], ac0[mi][ni], 0, 0, 0);
                        ac1[mi][ni] = __builtin_amdgcn_mfma_f32_16x16x32_bf16(av[mi], bv1[ni], ac1[mi][ni], 0, 0, 0);
                    }
            }
            __syncthreads();
        }
#pragma unroll
        for (int ni = 0; ni < 2; ++ni)
#pragma unroll
            for (int mi = 0; mi < 4; ++mi)
#pragma unroll
                for (int i = 0; i < 4; ++i) {
                    float mn = fminf(ac0[mi][ni][i], ac1[mi][ni][i]);
                    float mx = fmaxf(ac0[mi][ni][i], ac1[mi][ni][i]);
                    hmn[mi][ni][i] = fminf(hmn[mi][ni][i], mn);
                    hmx[mi][ni][i] = fmaxf(hmx[mi][ni][i], mx);
                }
    }

#pragma unroll
    for (int ni = 0; ni < 2; ++ni) {
        int col = n0 + wc * 32 + ni * 16 + frow;
#pragma unroll
        for (int mi = 0; mi < 4; ++mi) {
#pragma unroll
            for (int i = 0; i < 4; ++i) {
                int row = m0 + wr * 64 + mi * 16 + fq * 4 + i;
                float g = fmaxf(gelu_fast(hmn[mi][ni][i]), gelu_fast(hmx[mi][ni][i]));
                out[(size_t)row * Nc + col] = f2bf(g);
            }
        }
    }
}

// ---------------- LayerNorm over H=512: f32 in -> bf16 out ----------------
__global__ __launch_bounds__(256) void layernorm_bf16(const float* __restrict__ h,
                                                      unsigned short* __restrict__ o,
                                                      const float* __restrict__ g,
                                                      const float* __restrict__ b) {
    int row = blockIdx.x;
    const float* p = h + (size_t)row * 512;
    int tid = threadIdx.x;
    float v0 = p[tid], v1 = p[tid + 256];
    float s = v0 + v1, sq = v0 * v0 + v1 * v1;
#pragma unroll
    for (int off = 32; off >= 1; off >>= 1) {
        s += __shfl_xor(s, off);
        sq += __shfl_xor(sq, off);
    }
    __shared__ float ls[4], lq[4];
    int wid = tid >> 6, lane = tid & 63;
    if (lane == 0) { ls[wid] = s; lq[wid] = sq; }
    __syncthreads();
    float ts = ls[0] + ls[1] + ls[2] + ls[3];
    float tq = lq[0] + lq[1] + lq[2] + lq[3];
    float mean = ts / 512.f;
    float var = tq / 512.f - mean * mean;
    float inv = rsqrtf(var + 1e-5f);
    unsigned short* op = o + (size_t)row * 512;
    op[tid] = f2bf((v0 - mean) * inv * g[tid] + b[tid]);
    op[tid + 256] = f2bf((v1 - mean) * inv * g[tid + 256] + b[tid + 256]);
}

extern "C" void kernel_launch(void* const* d_in, const int* in_sizes, int n_in,
                              void* d_out, int out_size, void* d_ws, size_t ws_size,
                              hipStream_t stream) {
    const float* x        = (const float*)d_in[0];
    const int*   arows    = (const int*)d_in[1];
    const int*   acols    = (const int*)d_in[2];
    const float* avals    = (const float*)d_in[3];
    const float* basisenc = (const float*)d_in[4];
    const float* ln_g     = (const float*)d_in[5];
    const float* ln_b     = (const float*)d_in[6];
    const float* Wd_enc   = (const float*)d_in[7];
    const float* bd_enc   = (const float*)d_in[8];
    const float* W_mu     = (const float*)d_in[9];
    const float* b_mu     = (const float*)d_in[10];
    const float* W_lv     = (const float*)d_in[11];
    const float* b_lv     = (const float*)d_in[12];
    const float* Wd_dec   = (const float*)d_in[13];
    const float* bd_dec   = (const float*)d_in[14];
    const float* basisdec = (const float*)d_in[15];
    const float* epsin    = (const float*)d_in[16];

    const int N = 16384;
    const int E = in_sizes[1];

    float* ws = (float*)d_ws;
    const size_t A0 = 0;                               // f32 N*768: hF
    const size_t B0 = A0 + (size_t)N * 768;            // u16 N*800: cenc -> [cdec | zb]
    const size_t C0 = B0 + (size_t)N * 400;            // u16: xbf -> [hbf | encb] -> decb
    const size_t F0 = C0 + (size_t)N * 387;            // u16 weights
    const size_t G0 = F0 + 3100672;                    // CSR

    float* hF  = ws + A0;
    unsigned short* cenc = (unsigned short*)(ws + B0);
    unsigned short* cdec = (unsigned short*)(ws + B0);
    unsigned short* zb   = cdec + (size_t)N * 544;
    unsigned short* xbf  = (unsigned short*)(ws + C0);
    unsigned short* hbf  = (unsigned short*)(ws + C0);
    unsigned short* encb = hbf + (size_t)N * 512;
    unsigned short* decb = (unsigned short*)(ws + C0);
    unsigned short* wF = (unsigned short*)(ws + F0);
    unsigned short* BceT   = wF;                       // 512*800
    unsigned short* BcdT   = BceT + 512 * 800;         // 768*544
    unsigned short* WdencT = BcdT + 768 * 544;         // 20*256*512
    unsigned short* WddecT = WdencT + 20 * 256 * 512;  // 20*512*256
    unsigned short* WmuT   = WddecT + 20 * 512 * 256;  // 256*256
    unsigned short* WlvT   = WmuT + 256 * 256;         // contiguous -> [512,256]
    int*   csr_cnt  = (int*)(ws + G0);
    int*   csr_offs = csr_cnt + N;
    int*   csr_cur  = csr_offs + N + 1;
    int*   csr_col  = csr_cur + N;
    float* csr_val  = (float*)(csr_col + E);

    float* out_recon = (float*)d_out;
    float* out_mu    = out_recon + (size_t)N * 768;
    float* out_lv    = out_mu + (size_t)N * 256;

    // --- packs + cast ---
    {
        Bounds be = {{0, 54, 108, 210, 407, 794}};
        pack_basis_t<<<dim3(13, 8), 256, 0, stream>>>(basisenc, BceT, be, 768, 512, 794, 800);
        Bounds bdd = {{0, 38, 76, 146, 279, 538}};
        pack_basis_t<<<dim3(9, 12), 256, 0, stream>>>(basisdec, BcdT, bdd, 512, 768, 538, 544);
        pack_wT_t<<<dim3(8, 4, 20), 256, 0, stream>>>(Wd_enc, WdencT, 512, 256, 512);
        pack_wT_t<<<dim3(4, 8, 20), 256, 0, stream>>>(Wd_dec, WddecT, 256, 512, 256);
        pack_wT_t<<<dim3(4, 4, 1), 256, 0, stream>>>(W_mu, WmuT, 256, 256, 256);
        pack_wT_t<<<dim3(4, 4, 1), 256, 0, stream>>>(W_lv, WlvT, 256, 256, 256);
        cast_bf16_kernel<<<(N * 768 / 4 + 255) / 256, 256, 0, stream>>>(x, xbf, N * 768 / 4);
    }

    // 1) CSR build + fused SpMM+wavedec-enc -> cenc
    hipMemsetAsync(csr_cnt, 0, N * sizeof(int), stream);
    hist_kernel<<<(E + 255) / 256, 256, 0, stream>>>(arows, csr_cnt, E);
    scan_kernel<<<1, 1024, 0, stream>>>(csr_cnt, csr_offs, csr_cur, N, E);
    scatter_kernel<<<(E + 255) / 256, 256, 0, stream>>>(arows, acols, avals, csr_cur, csr_col, csr_val, E);
    spmm_wavedec_enc<<<N / 4, 256, 0, stream>>>(xbf, csr_offs, csr_col, csr_val, cenc);

    // 2) h = cenc @ BceT^T  [16384,512], K=800.  nwg = 512
    gemm_mfma<0><<<(512 / 128) * (N / 128), 256, 0, stream>>>(cenc, BceT, nullptr, nullptr, hF, nullptr,
                                                              N, 512, 800, 800, 800, 512, 512 / 128);

    // 3) layernorm -> bf16
    layernorm_bf16<<<N, 256, 0, stream>>>(hF, hbf, ln_g, ln_b);

    // 4) enc dendritic (K=512): all 20 branches, dual-branch.  nwg = 512
    dendritic_full<<<4 * (N / 128), 256, 0, stream>>>(hbf, WdencT, bd_enc, encb, N, 256, 512, 20, 4);

    // 5) mu & logvar: single-B GEMM over [WmuT|WlvT] = [512,256], split epilogue.  nwg = 512
    gemm_mfma<2><<<(512 / 128) * (N / 128), 256, 0, stream>>>(encb, WmuT, b_mu, b_lv, out_mu, out_lv,
                                                              N, 512, 256, 256, 256, 256, 512 / 128);

    // 6) z -> bf16
    z_kernel<<<(N * 256 / 4 + 255) / 256, 256, 0, stream>>>(out_mu, out_lv, epsin, zb, N * 256 / 4);

    // 7) dec dendritic (K=256): A-resident LDS.  nwg = 1024
    dendritic_dec_res<<<8 * (N / 128), 256, 0, stream>>>(zb, WddecT, bd_dec, decb, N, 512, 20, 8);

    // 8) fused wavedec-dec -> cdec
    wavedec_dec<<<N / 4, 256, 0, stream>>>(decb, cdec);

    // 9) recon = cdec @ BcdT^T [16384,768], K=544.  nwg = 768
    gemm_mfma<0><<<(768 / 128) * (N / 128), 256, 0, stream>>>(cdec, BcdT, nullptr, nullptr, out_recon, nullptr,
                                                              N, 768, 544, 544, 544, 768, 768 / 128);

    (void)ws_size; (void)out_size; (void)n_in;
}

// Round 16
// 457.284 us; speedup vs baseline: 1.0701x; 1.0595x over previous
//
#include <hip/hip_runtime.h>

typedef __attribute__((ext_vector_type(8))) short short8v;
typedef __attribute__((ext_vector_type(8))) unsigned short ushort8v;
typedef __attribute__((ext_vector_type(4))) float float4v;

__device__ __constant__ float c_LO[8] = {
    -0.010597401784997278f, 0.032883011666982945f, 0.030841381835986965f,
    -0.18703481171888114f, -0.02798376941698385f, 0.6308807679295904f,
    0.7148465705525415f, 0.23037781330885523f};
__device__ __constant__ float c_HI[8] = {
    -0.23037781330885523f, 0.7148465705525415f, -0.6308807679295904f,
    -0.02798376941698385f, 0.18703481171888114f, 0.030841381835986965f,
    -0.032883011666982945f, -0.010597401784997278f};

__device__ __forceinline__ unsigned short f2bf(float f) {
    unsigned u = __builtin_bit_cast(unsigned, f);
    unsigned r = u + 0x7fffu + ((u >> 16) & 1u);
    return (unsigned short)(r >> 16);
}
__device__ __forceinline__ float bf2f(unsigned short u) {
    return __builtin_bit_cast(float, (unsigned)u << 16);
}

__device__ __forceinline__ float gelu_fast(float x) {
    float x3 = x * x * x;
    float y = fmaf(0.044715f, x3, x) * 0.7978845608028654f;
    float t = fminf(fmaxf(y * 2.8853900817779268f, -30.f), 30.f);
    float e = exp2f(t);
    return x * e * __builtin_amdgcn_rcpf(e + 1.0f);
}

__device__ __forceinline__ void gload_lds16(const void* g, void* l) {
    __builtin_amdgcn_global_load_lds(g, l, 16, 0, 0);
}

// ---- one DWT level helpers (pywt symmetric) ----
__device__ __forceinline__ void dwt_lvl(const float* __restrict__ in, int n, float* __restrict__ outA,
                                        unsigned short* __restrict__ outD, int m, int lane) {
    for (int j = lane; j < m; j += 64) {
        float a = 0.f, d = 0.f;
#pragma unroll
        for (int i = 0; i < 8; ++i) {
            int p = 2 * j + 7 - i;
            int q = (p < 6) ? (5 - p) : ((p < n + 6) ? (p - 6) : (2 * n + 5 - p));
            float xv = in[q];
            a = fmaf(c_LO[i], xv, a);
            d = fmaf(c_HI[i], xv, d);
        }
        outA[j] = a;
        outD[j] = f2bf(d);
    }
}
__device__ __forceinline__ void dwt_lvl_final(const float* __restrict__ in, int n, unsigned short* __restrict__ outA,
                                              unsigned short* __restrict__ outD, int m, int lane) {
    for (int j = lane; j < m; j += 64) {
        float a = 0.f, d = 0.f;
#pragma unroll
        for (int i = 0; i < 8; ++i) {
            int p = 2 * j + 7 - i;
            int q = (p < 6) ? (5 - p) : ((p < n + 6) ? (p - 6) : (2 * n + 5 - p));
            float xv = in[q];
            a = fmaf(c_LO[i], xv, a);
            d = fmaf(c_HI[i], xv, d);
        }
        outA[j] = f2bf(a);
        outD[j] = f2bf(d);
    }
}

// ---------------- CSR build ----------------
__global__ void hist_kernel(const int* __restrict__ rows, int* __restrict__ cnt, int E) {
    int i = blockIdx.x * blockDim.x + threadIdx.x;
    if (i < E) atomicAdd(&cnt[rows[i]], 1);
}

__global__ __launch_bounds__(1024) void scan_kernel(const int* __restrict__ cnt, int* __restrict__ offs,
                                                    int* __restrict__ cursor, int Nrows, int E) {
    __shared__ int part[1024];
    int tid = threadIdx.x;
    const int per = Nrows / 1024;  // 16
    int base = tid * per;
    int local[16];
    int s = 0;
    for (int i = 0; i < per; ++i) { local[i] = s; s += cnt[base + i]; }
    part[tid] = s;
    __syncthreads();
    for (int off = 1; off < 1024; off <<= 1) {
        int v = part[tid];
        int w = (tid >= off) ? part[tid - off] : 0;
        __syncthreads();
        part[tid] = v + w;
        __syncthreads();
    }
    int pre = (tid == 0) ? 0 : part[tid - 1];
    for (int i = 0; i < per; ++i) {
        int o = pre + local[i];
        offs[base + i] = o;
        cursor[base + i] = o;
    }
    if (tid == 0) offs[Nrows] = E;
}

__global__ void scatter_kernel(const int* __restrict__ rows, const int* __restrict__ cols,
                               const float* __restrict__ vals, int* __restrict__ cursor,
                               int* __restrict__ ccol, float* __restrict__ cval, int E) {
    int i = blockIdx.x * blockDim.x + threadIdx.x;
    if (i >= E) return;
    int r = rows[i];
    int p = atomicAdd(&cursor[r], 1);
    ccol[p] = cols[i];
    cval[p] = vals[i];
}

// ---- 4-level wavedec of x (f32 in, coalesced) -> cenc bf16 [N,800] ----
// Linearity: wavekan(A x) == A wavekan(x); SpMM moved after the basis GEMM.
__global__ __launch_bounds__(256) void wavedec_enc_x(const float* __restrict__ x,
                                                     unsigned short* __restrict__ cenc) {
    __shared__ float buf0[4][768];
    __shared__ float buf1[4][400];
    const int widx = threadIdx.x >> 6, lane = threadIdx.x & 63;
    const int r = blockIdx.x * 4 + widx;
    float* b0 = buf0[widx];
    float* b1 = buf1[widx];
    const float* ip = x + (size_t)r * 768;
    for (int i = lane; i < 768; i += 64) b0[i] = ip[i];
    __syncthreads();
    unsigned short* cr = cenc + (size_t)r * 800;
    dwt_lvl(b0, 768, b1, cr + 407, 387, lane);
    __syncthreads();
    dwt_lvl(b1, 387, b0, cr + 210, 197, lane);
    __syncthreads();
    dwt_lvl(b0, 197, b1, cr + 108, 102, lane);
    __syncthreads();
    dwt_lvl_final(b1, 102, cr + 0, cr + 54, 54, lane);
    if (lane < 6) cr[794 + lane] = 0;
}

// ---- FUSED SpMM gather (512-wide bf16 rows of hx) + LayerNorm -> hbf bf16 ----
// one wave per output row; row lives in registers (8 f32/lane); shuffle-reduce LN.
__global__ __launch_bounds__(256) void spmm_ln(const unsigned short* __restrict__ hx,
                                               const int* __restrict__ offs,
                                               const int* __restrict__ ccol,
                                               const float* __restrict__ cval,
                                               const float* __restrict__ g,
                                               const float* __restrict__ b,
                                               unsigned short* __restrict__ hbf) {
    const int widx = threadIdx.x >> 6, lane = threadIdx.x & 63;
    const int r = blockIdx.x * 4 + widx;
    int s = offs[r], e = offs[r + 1];
    float acc[8] = {};
    for (int j = s; j < e; ++j) {
        int c = ccol[j];
        float v = cval[j];
        ushort8v u = *(const ushort8v*)(hx + (size_t)c * 512 + lane * 8);
#pragma unroll
        for (int t = 0; t < 8; ++t) acc[t] = fmaf(v, bf2f(u[t]), acc[t]);
    }
    float s1 = 0.f, s2 = 0.f;
#pragma unroll
    for (int t = 0; t < 8; ++t) { s1 += acc[t]; s2 = fmaf(acc[t], acc[t], s2); }
#pragma unroll
    for (int off = 32; off >= 1; off >>= 1) {
        s1 += __shfl_xor(s1, off);
        s2 += __shfl_xor(s2, off);
    }
    float mean = s1 * (1.f / 512.f);
    float var = s2 * (1.f / 512.f) - mean * mean;
    float inv = rsqrtf(var + 1e-5f);
    ushort8v o;
#pragma unroll
    for (int t = 0; t < 8; ++t) {
        int col = lane * 8 + t;
        o[t] = f2bf((acc[t] - mean) * inv * g[col] + b[col]);
    }
    *(ushort8v*)(hbf + (size_t)r * 512 + lane * 8) = o;
}

// ---- FUSED: 4-level wavedec of dec (bf16 in) -> cdec bf16 [N,544] ----
__global__ __launch_bounds__(256) void wavedec_dec(const unsigned short* __restrict__ decb,
                                                   unsigned short* __restrict__ cdec) {
    __shared__ float buf0[4][512];
    __shared__ float buf1[4][272];
    const int widx = threadIdx.x >> 6, lane = threadIdx.x & 63;
    const int r = blockIdx.x * 4 + widx;
    float* b0 = buf0[widx];
    float* b1 = buf1[widx];
    const unsigned short* ip = decb + (size_t)r * 512;
    for (int i = lane; i < 512; i += 64) b0[i] = bf2f(ip[i]);
    __syncthreads();
    unsigned short* cr = cdec + (size_t)r * 544;
    dwt_lvl(b0, 512, b1, cr + 279, 259, lane);
    __syncthreads();
    dwt_lvl(b1, 259, b0, cr + 146, 133, lane);
    __syncthreads();
    dwt_lvl(b0, 133, b1, cr + 76, 70, lane);
    __syncthreads();
    dwt_lvl_final(b1, 70, cr + 0, cr + 38, 38, lane);
    if (lane < 6) cr[538 + lane] = 0;
}

// ---------------- LDS-tiled transpose packs ----------------
struct Bounds { int b[6]; };

__global__ __launch_bounds__(256) void pack_wT_t(const float* __restrict__ W, unsigned short* __restrict__ WT,
                                                 int K, int N, int Kpad) {
    __shared__ float t[64][65];
    const int b = blockIdx.z;
    const int k0 = blockIdx.x * 64, n0 = blockIdx.y * 64;
    const int tid = threadIdx.x;
#pragma unroll
    for (int i = 0; i < 16; ++i) {
        int idx = tid + i * 256;
        int kk = idx >> 6, nn = idx & 63;
        int k = k0 + kk;
        t[kk][nn] = (k < K) ? W[((size_t)b * K + k) * N + n0 + nn] : 0.f;
    }
    __syncthreads();
#pragma unroll
    for (int i = 0; i < 16; ++i) {
        int idx = tid + i * 256;
        int nn = idx >> 6, kk = idx & 63;
        int k = k0 + kk;
        if (k < Kpad)
            WT[((size_t)b * N + n0 + nn) * Kpad + k] = f2bf(t[kk][nn]);
    }
}

__global__ __launch_bounds__(256) void pack_basis_t(const float* __restrict__ basis, unsigned short* __restrict__ BT,
                                                    Bounds bd, int brows, int N, int K, int Kpad) {
    __shared__ float t[64][65];
    const int k0 = blockIdx.x * 64, n0 = blockIdx.y * 64;
    const int tid = threadIdx.x;
#pragma unroll
    for (int i = 0; i < 16; ++i) {
        int idx = tid + i * 256;
        int kk = idx >> 6, nn = idx & 63;
        int k = k0 + kk;
        float v = 0.f;
        if (k < K) {
            int s = 0;
#pragma unroll
            for (int u = 1; u < 5; ++u)
                if (k >= bd.b[u]) s = u;
            int lr = k - bd.b[s];
            v = basis[((size_t)s * brows + lr) * N + n0 + nn];
        }
        t[kk][nn] = v;
    }
    __syncthreads();
#pragma unroll
    for (int i = 0; i < 16; ++i) {
        int idx = tid + i * 256;
        int nn = idx >> 6, kk = idx & 63;
        int k = k0 + kk;
        if (k < Kpad)
            BT[(size_t)(n0 + nn) * Kpad + k] = f2bf(t[kk][nn]);
    }
}

// ---------------- bf16 MFMA GEMM, 1D grid + m-major XCD swizzle ----------------
// MODE 0: f32 out. MODE 1: bf16 out. MODE 2: mu/lv split epilogue.
template <int MODE>
__global__ __launch_bounds__(256) void gemm_mfma(const unsigned short* __restrict__ A,
                                                 const unsigned short* __restrict__ BT,
                                                 const float* __restrict__ bias,
                                                 const float* __restrict__ bias2,
                                                 void* __restrict__ Cv, void* __restrict__ Cv2,
                                                 int M, int N, int K, int lda, int ldb, int ldc, int nx) {
    __shared__ __align__(16) unsigned short As[128 * 32];
    __shared__ __align__(16) unsigned short Bs[128 * 32];
    const int tid = threadIdx.x;
    const int wave = tid >> 6, lane = tid & 63;
    const int nwg = gridDim.x;
    const int logical = (blockIdx.x & 7) * (nwg >> 3) + (blockIdx.x >> 3);
    const int mblk = logical / nx, nblk = logical - mblk * nx;
    const int m0 = mblk * 128, n0 = nblk * 128;
    const int wr = wave >> 1, wc = wave & 1;
    const int frow = lane & 15, fq = lane >> 4;

    const int off0 = tid * 16;
    const int r0 = off0 >> 6, c0 = off0 & 63;
    const int r1 = (off0 + 4096) >> 6, c1 = (off0 + 4096) & 63;
    const char* Ab = (const char*)A;
    const char* Bb = (const char*)BT;
    size_t gA0 = (size_t)(m0 + r0) * lda * 2 + c0;
    size_t gA1 = (size_t)(m0 + r1) * lda * 2 + c1;
    size_t gB0 = (size_t)(n0 + r0) * ldb * 2 + c0;
    size_t gB1 = (size_t)(n0 + r1) * ldb * 2 + c1;
    char* lA0 = (char*)As + wave * 1024;
    char* lB0 = (char*)Bs + wave * 1024;

    const int aoff = (wr * 64 + frow) * 32 + fq * 8;
    const int boff = (wc * 64 + frow) * 32 + fq * 8;

    float4v acc[4][4] = {};
    for (int k0 = 0; k0 < K; k0 += 32) {
        size_t kb2 = (size_t)k0 * 2;
        gload_lds16(Ab + gA0 + kb2, lA0);
        gload_lds16(Ab + gA1 + kb2, lA0 + 4096);
        gload_lds16(Bb + gB0 + kb2, lB0);
        gload_lds16(Bb + gB1 + kb2, lB0 + 4096);
        __syncthreads();
        short8v av[4], bv[4];
#pragma unroll
        for (int i = 0; i < 4; ++i) av[i] = *(const short8v*)(As + aoff + i * 512);
#pragma unroll
        for (int i = 0; i < 4; ++i) bv[i] = *(const short8v*)(Bs + boff + i * 512);
#pragma unroll
        for (int mi = 0; mi < 4; ++mi)
#pragma unroll
            for (int ni = 0; ni < 4; ++ni)
                acc[mi][ni] = __builtin_amdgcn_mfma_f32_16x16x32_bf16(av[mi], bv[ni], acc[mi][ni], 0, 0, 0);
        __syncthreads();
    }
#pragma unroll
    for (int ni = 0; ni < 4; ++ni) {
        int col = n0 + wc * 64 + ni * 16 + frow;
#pragma unroll
        for (int mi = 0; mi < 4; ++mi) {
#pragma unroll
            for (int i = 0; i < 4; ++i) {
                int row = m0 + wr * 64 + mi * 16 + fq * 4 + i;
                if (MODE == 0) {
                    ((float*)Cv)[(size_t)row * ldc + col] = acc[mi][ni][i];
                } else if (MODE == 1) {
                    ((unsigned short*)Cv)[(size_t)row * ldc + col] = f2bf(acc[mi][ni][i]);
                } else {
                    bool isMu = col < 256;
                    int coll = col & 255;
                    float bval = isMu ? bias[coll] : bias2[coll];
                    float* dst = (float*)(isMu ? Cv : Cv2);
                    dst[(size_t)row * 256 + coll] = acc[mi][ni][i] + bval;
                }
            }
        }
    }
}

// ---------------- z = mu + eps * exp(0.5*logvar)  -> bf16 ----------------
__global__ void z_kernel(const float* __restrict__ mu, const float* __restrict__ lv,
                         const float* __restrict__ eps, unsigned short* __restrict__ z, int n4) {
    int i = blockIdx.x * blockDim.x + threadIdx.x;
    if (i >= n4) return;
    float4 m = ((const float4*)mu)[i];
    float4 l = ((const float4*)lv)[i];
    float4 e = ((const float4*)eps)[i];
    ushort4 o;
    o.x = f2bf(m.x + e.x * expf(0.5f * l.x));
    o.y = f2bf(m.y + e.y * expf(0.5f * l.y));
    o.z = f2bf(m.z + e.z * expf(0.5f * l.z));
    o.w = f2bf(m.w + e.w * expf(0.5f * l.w));
    ((ushort4*)z)[i] = o;
}

// ---- dendritic enc (K=512): dual-branch, all 20 branches ----
__global__ __launch_bounds__(256, 2) void dendritic_full(const unsigned short* __restrict__ A,
                                                         const unsigned short* __restrict__ WT,
                                                         const float* __restrict__ bias,
                                                         unsigned short* __restrict__ out,
                                                         int M, int Nc, int K, int nb, int nx) {
    __shared__ __align__(16) unsigned short As[128 * 64];
    __shared__ __align__(16) unsigned short Bs[2][64 * 64];
    const int tid = threadIdx.x;
    const int wave = tid >> 6;
    const int lane = tid & 63;

    const int nwg = gridDim.x;
    const int logical = (blockIdx.x & 7) * (nwg >> 3) + (blockIdx.x >> 3);
    const int mblk = logical / nx;
    const int nblk = logical - mblk * nx;
    const int n0 = nblk * 64, m0 = mblk * 128;

    const int wr = wave >> 1, wc = wave & 1;
    const int frow = lane & 15, fq = lane >> 4;

    int srA[4], scA[4];
#pragma unroll
    for (int i = 0; i < 4; ++i) {
        int ch = i * 256 + tid;
        srA[i] = ch >> 3;
        scA[i] = ((ch & 7) ^ (srA[i] & 7)) * 16;
    }
    int srB[2], scB[2];
#pragma unroll
    for (int i = 0; i < 2; ++i) {
        int ch = i * 256 + tid;
        srB[i] = ch >> 3;
        scB[i] = ((ch & 7) ^ (srB[i] & 7)) * 16;
    }
    const char* Ab = (const char*)A;
    const size_t K2 = (size_t)K * 2;
    const size_t branchBytes = (size_t)Nc * K2;
    char* lA  = (char*)As + wave * 1024;
    char* lB0 = (char*)&Bs[0][0] + wave * 1024;
    char* lB1 = (char*)&Bs[1][0] + wave * 1024;

    float4v hmn[4][2], hmx[4][2];
#pragma unroll
    for (int mi = 0; mi < 4; ++mi)
#pragma unroll
        for (int ni = 0; ni < 2; ++ni) { hmn[mi][ni] = (float4v)(1e30f); hmx[mi][ni] = (float4v)(-1e30f); }

    const int npair = nb >> 1;
    for (int p = 0; p < npair; ++p) {
        const int b0 = 2 * p, b1 = 2 * p + 1;
        const char* Bb0 = (const char*)WT + (size_t)b0 * branchBytes;
        const char* Bb1 = (const char*)WT + (size_t)b1 * branchBytes;
        float4v ac0[4][2], ac1[4][2];
#pragma unroll
        for (int ni = 0; ni < 2; ++ni) {
            int col = n0 + wc * 32 + ni * 16 + frow;
            float bv0 = bias[(size_t)b0 * Nc + col];
            float bv1 = bias[(size_t)b1 * Nc + col];
#pragma unroll
            for (int mi = 0; mi < 4; ++mi) { ac0[mi][ni] = (float4v)(bv0); ac1[mi][ni] = (float4v)(bv1); }
        }
        for (int k0 = 0; k0 < K; k0 += 64) {
            const size_t kby = (size_t)k0 * 2;
#pragma unroll
            for (int i = 0; i < 4; ++i)
                gload_lds16(Ab + (size_t)(m0 + srA[i]) * K2 + kby + scA[i], lA + i * 4096);
#pragma unroll
            for (int i = 0; i < 2; ++i)
                gload_lds16(Bb0 + (size_t)(n0 + srB[i]) * K2 + kby + scB[i], lB0 + i * 4096);
#pragma unroll
            for (int i = 0; i < 2; ++i)
                gload_lds16(Bb1 + (size_t)(n0 + srB[i]) * K2 + kby + scB[i], lB1 + i * 4096);
            __syncthreads();
#pragma unroll
            for (int kk = 0; kk < 2; ++kk) {
                short8v av[4], bv0[2], bv1[2];
                const int slot = kk * 4 + fq;
#pragma unroll
                for (int mi = 0; mi < 4; ++mi) {
                    int ra = wr * 64 + mi * 16 + frow;
                    av[mi] = *(const short8v*)((const char*)As + ra * 128 + ((slot ^ (ra & 7)) * 16));
                }
#pragma unroll
                for (int ni = 0; ni < 2; ++ni) {
                    int rb = wc * 32 + ni * 16 + frow;
                    int rboff = rb * 128 + ((slot ^ (rb & 7)) * 16);
                    bv0[ni] = *(const short8v*)((const char*)&Bs[0][0] + rboff);
                    bv1[ni] = *(const short8v*)((const char*)&Bs[1][0] + rboff);
                }
#pragma unroll
                for (int mi = 0; mi < 4; ++mi)
#pragma unroll
                    for (int ni = 0; ni < 2; ++ni) {
                        ac0[mi][ni] = __builtin_amdgcn_mfma_f32_16x16x32_bf16(av[mi], bv0[ni], ac0[mi][ni], 0, 0, 0);
                        ac1[mi][ni] = __builtin_amdgcn_mfma_f32_16x16x32_bf16(av[mi], bv1[ni], ac1[mi][ni], 0, 0, 0);
                    }
            }
            __syncthreads();
        }
#pragma unroll
        for (int ni = 0; ni < 2; ++ni)
#pragma unroll
            for (int mi = 0; mi < 4; ++mi)
#pragma unroll
                for (int i = 0; i < 4; ++i) {
                    float mn = fminf(ac0[mi][ni][i], ac1[mi][ni][i]);
                    float mx = fmaxf(ac0[mi][ni][i], ac1[mi][ni][i]);
                    hmn[mi][ni][i] = fminf(hmn[mi][ni][i], mn);
                    hmx[mi][ni][i] = fmaxf(hmx[mi][ni][i], mx);
                }
    }

#pragma unroll
    for (int ni = 0; ni < 2; ++ni) {
        int col = n0 + wc * 32 + ni * 16 + frow;
#pragma unroll
        for (int mi = 0; mi < 4; ++mi) {
#pragma unroll
            for (int i = 0; i < 4; ++i) {
                int row = m0 + wr * 64 + mi * 16 + fq * 4 + i;
                float g = fmaxf(gelu_fast(hmn[mi][ni][i]), gelu_fast(hmx[mi][ni][i]));
                out[(size_t)row * Nc + col] = f2bf(g);
            }
        }
    }
}

// ---- dendritic dec (K=256): A-tile RESIDENT in LDS (64 KB), B dual streamed ----
__global__ __launch_bounds__(256, 2) void dendritic_dec_res(const unsigned short* __restrict__ A,
                                                            const unsigned short* __restrict__ WT,
                                                            const float* __restrict__ bias,
                                                            unsigned short* __restrict__ out,
                                                            int M, int Nc, int nb, int nx) {
    constexpr int K = 256;
    __shared__ __align__(16) unsigned short As[128 * 256];
    __shared__ __align__(16) unsigned short Bs[2][64 * 64];
    const int tid = threadIdx.x;
    const int wave = tid >> 6;
    const int lane = tid & 63;

    const int nwg = gridDim.x;
    const int logical = (blockIdx.x & 7) * (nwg >> 3) + (blockIdx.x >> 3);
    const int mblk = logical / nx;
    const int nblk = logical - mblk * nx;
    const int n0 = nblk * 64, m0 = mblk * 128;

    const int wr = wave >> 1, wc = wave & 1;
    const int frow = lane & 15, fq = lane >> 4;

    const char* Ab = (const char*)A;
    const size_t K2 = (size_t)K * 2;
    for (int i = 0; i < 16; ++i) {
        int ch = i * 256 + tid;
        int row = ch >> 5, slot = ch & 31;
        int sslot = (slot & ~7) | ((slot & 7) ^ (row & 7));
        gload_lds16(Ab + (size_t)(m0 + row) * K2 + sslot * 16, (char*)As + i * 4096 + wave * 1024);
    }

    int srB[2], scB[2];
#pragma unroll
    for (int i = 0; i < 2; ++i) {
        int ch = i * 256 + tid;
        srB[i] = ch >> 3;
        scB[i] = ((ch & 7) ^ (srB[i] & 7)) * 16;
    }
    const size_t branchBytes = (size_t)Nc * K2;
    char* lB0 = (char*)&Bs[0][0] + wave * 1024;
    char* lB1 = (char*)&Bs[1][0] + wave * 1024;

    float4v hmn[4][2], hmx[4][2];
#pragma unroll
    for (int mi = 0; mi < 4; ++mi)
#pragma unroll
        for (int ni = 0; ni < 2; ++ni) { hmn[mi][ni] = (float4v)(1e30f); hmx[mi][ni] = (float4v)(-1e30f); }

    const int npair = nb >> 1;
    for (int p = 0; p < npair; ++p) {
        const int b0 = 2 * p, b1 = 2 * p + 1;
        const char* Bb0 = (const char*)WT + (size_t)b0 * branchBytes;
        const char* Bb1 = (const char*)WT + (size_t)b1 * branchBytes;
        float4v ac0[4][2], ac1[4][2];
#pragma unroll
        for (int ni = 0; ni < 2; ++ni) {
            int col = n0 + wc * 32 + ni * 16 + frow;
            float bv0 = bias[(size_t)b0 * Nc + col];
            float bv1 = bias[(size_t)b1 * Nc + col];
#pragma unroll
            for (int mi = 0; mi < 4; ++mi) { ac0[mi][ni] = (float4v)(bv0); ac1[mi][ni] = (float4v)(bv1); }
        }
        for (int k0 = 0; k0 < K; k0 += 64) {
            const size_t kby = (size_t)k0 * 2;
#pragma unroll
            for (int i = 0; i < 2; ++i)
                gload_lds16(Bb0 + (size_t)(n0 + srB[i]) * K2 + kby + scB[i], lB0 + i * 4096);
#pragma unroll
            for (int i = 0; i < 2; ++i)
                gload_lds16(Bb1 + (size_t)(n0 + srB[i]) * K2 + kby + scB[i], lB1 + i * 4096);
            __syncthreads();
#pragma unroll
            for (int kk = 0; kk < 2; ++kk) {
                short8v av[4], bv0[2], bv1[2];
                const int slot = kk * 4 + fq;
#pragma unroll
                for (int mi = 0; mi < 4; ++mi) {
                    int ra = wr * 64 + mi * 16 + frow;
                    int g = (k0 >> 3) + slot;
                    int sl = (g & ~7) | ((g & 7) ^ (ra & 7));
                    av[mi] = *(const short8v*)((const char*)As + ra * 512 + sl * 16);
                }
#pragma unroll
                for (int ni = 0; ni < 2; ++ni) {
                    int rb = wc * 32 + ni * 16 + frow;
                    int rboff = rb * 128 + ((slot ^ (rb & 7)) * 16);
                    bv0[ni] = *(const short8v*)((const char*)&Bs[0][0] + rboff);
                    bv1[ni] = *(const short8v*)((const char*)&Bs[1][0] + rboff);
                }
#pragma unroll
                for (int mi = 0; mi < 4; ++mi)
#pragma unroll
                    for (int ni = 0; ni < 2; ++ni) {
                        ac0[mi][ni] = __builtin_amdgcn_mfma_f32_16x16x32_bf16(av[mi], bv0[ni], ac0[mi][ni], 0, 0, 0);
                        ac1[mi][ni] = __builtin_amdgcn_mfma_f32_16x16x32_bf16(av[mi], bv1[ni], ac1[mi][ni], 0, 0, 0);
                    }
            }
            __syncthreads();
        }
#pragma unroll
        for (int ni = 0; ni < 2; ++ni)
#pragma unroll
            for (int mi = 0; mi < 4; ++mi)
#pragma unroll
                for (int i = 0; i < 4; ++i) {
                    float mn = fminf(ac0[mi][ni][i], ac1[mi][ni][i]);
                    float mx = fmaxf(ac0[mi][ni][i], ac1[mi][ni][i]);
                    hmn[mi][ni][i] = fminf(hmn[mi][ni][i], mn);
                    hmx[mi][ni][i] = fmaxf(hmx[mi][ni][i], mx);
                }
    }

#pragma unroll
    for (int ni = 0; ni < 2; ++ni) {
        int col = n0 + wc * 32 + ni * 16 + frow;
#pragma unroll
        for (int mi = 0; mi < 4; ++mi) {
#pragma unroll
            for (int i = 0; i < 4; ++i) {
                int row = m0 + wr * 64 + mi * 16 + fq * 4 + i;
                float g = fmaxf(gelu_fast(hmn[mi][ni][i]), gelu_fast(hmx[mi][ni][i]));
                out[(size_t)row * Nc + col] = f2bf(g);
            }
        }
    }
}

extern "C" void kernel_launch(void* const* d_in, const int* in_sizes, int n_in,
                              void* d_out, int out_size, void* d_ws, size_t ws_size,
                              hipStream_t stream) {
    const float* x        = (const float*)d_in[0];
    const int*   arows    = (const int*)d_in[1];
    const int*   acols    = (const int*)d_in[2];
    const float* avals    = (const float*)d_in[3];
    const float* basisenc = (const float*)d_in[4];
    const float* ln_g     = (const float*)d_in[5];
    const float* ln_b     = (const float*)d_in[6];
    const float* Wd_enc   = (const float*)d_in[7];
    const float* bd_enc   = (const float*)d_in[8];
    const float* W_mu     = (const float*)d_in[9];
    const float* b_mu     = (const float*)d_in[10];
    const float* W_lv     = (const float*)d_in[11];
    const float* b_lv     = (const float*)d_in[12];
    const float* Wd_dec   = (const float*)d_in[13];
    const float* bd_dec   = (const float*)d_in[14];
    const float* basisdec = (const float*)d_in[15];
    const float* epsin    = (const float*)d_in[16];

    const int N = 16384;
    const int E = in_sizes[1];

    float* ws = (float*)d_ws;
    const size_t A0 = 0;                               // u16 N*512: hx (pre-aggregation h)
    const size_t B0 = A0 + (size_t)N * 768;            // u16 N*800: cenc -> [cdec | zb]
    const size_t C0 = B0 + (size_t)N * 400;            // u16: [hbf | encb] -> decb
    const size_t F0 = C0 + (size_t)N * 387;            // u16 weights
    const size_t G0 = F0 + 3100672;                    // CSR

    unsigned short* hx   = (unsigned short*)(ws + A0);  // [N,512] bf16
    unsigned short* cenc = (unsigned short*)(ws + B0);
    unsigned short* cdec = (unsigned short*)(ws + B0);
    unsigned short* zb   = cdec + (size_t)N * 544;
    unsigned short* hbf  = (unsigned short*)(ws + C0);
    unsigned short* encb = hbf + (size_t)N * 512;
    unsigned short* decb = (unsigned short*)(ws + C0);
    unsigned short* wF = (unsigned short*)(ws + F0);
    unsigned short* BceT   = wF;                       // 512*800
    unsigned short* BcdT   = BceT + 512 * 800;         // 768*544
    unsigned short* WdencT = BcdT + 768 * 544;         // 20*256*512
    unsigned short* WddecT = WdencT + 20 * 256 * 512;  // 20*512*256
    unsigned short* WmuT   = WddecT + 20 * 512 * 256;  // 256*256
    unsigned short* WlvT   = WmuT + 256 * 256;         // contiguous -> [512,256]
    int*   csr_cnt  = (int*)(ws + G0);
    int*   csr_offs = csr_cnt + N;
    int*   csr_cur  = csr_offs + N + 1;
    int*   csr_col  = csr_cur + N;
    float* csr_val  = (float*)(csr_col + E);

    float* out_recon = (float*)d_out;
    float* out_mu    = out_recon + (size_t)N * 768;
    float* out_lv    = out_mu + (size_t)N * 256;

    // --- packs ---
    {
        Bounds be = {{0, 54, 108, 210, 407, 794}};
        pack_basis_t<<<dim3(13, 8), 256, 0, stream>>>(basisenc, BceT, be, 768, 512, 794, 800);
        Bounds bdd = {{0, 38, 76, 146, 279, 538}};
        pack_basis_t<<<dim3(9, 12), 256, 0, stream>>>(basisdec, BcdT, bdd, 512, 768, 538, 544);
        pack_wT_t<<<dim3(8, 4, 20), 256, 0, stream>>>(Wd_enc, WdencT, 512, 256, 512);
        pack_wT_t<<<dim3(4, 8, 20), 256, 0, stream>>>(Wd_dec, WddecT, 256, 512, 256);
        pack_wT_t<<<dim3(4, 4, 1), 256, 0, stream>>>(W_mu, WmuT, 256, 256, 256);
        pack_wT_t<<<dim3(4, 4, 1), 256, 0, stream>>>(W_lv, WlvT, 256, 256, 256);
    }

    // 1) CSR build + wavedec of x (linearity: h = A · wavekan(x))
    hipMemsetAsync(csr_cnt, 0, N * sizeof(int), stream);
    hist_kernel<<<(E + 255) / 256, 256, 0, stream>>>(arows, csr_cnt, E);
    scan_kernel<<<1, 1024, 0, stream>>>(csr_cnt, csr_offs, csr_cur, N, E);
    scatter_kernel<<<(E + 255) / 256, 256, 0, stream>>>(arows, acols, avals, csr_cur, csr_col, csr_val, E);
    wavedec_enc_x<<<N / 4, 256, 0, stream>>>(x, cenc);

    // 2) hx = cenc @ BceT^T  [16384,512] bf16, K=800.  nwg = 512
    gemm_mfma<1><<<(512 / 128) * (N / 128), 256, 0, stream>>>(cenc, BceT, nullptr, nullptr, hx, nullptr,
                                                              N, 512, 800, 800, 800, 512, 512 / 128);

    // 3) fused SpMM gather (512-wide) + LayerNorm -> hbf
    spmm_ln<<<N / 4, 256, 0, stream>>>(hx, csr_offs, csr_col, csr_val, ln_g, ln_b, hbf);

    // 4) enc dendritic (K=512): all 20 branches, dual-branch.  nwg = 512
    dendritic_full<<<4 * (N / 128), 256, 0, stream>>>(hbf, WdencT, bd_enc, encb, N, 256, 512, 20, 4);

    // 5) mu & logvar: single-B GEMM over [WmuT|WlvT] = [512,256], split epilogue.  nwg = 512
    gemm_mfma<2><<<(512 / 128) * (N / 128), 256, 0, stream>>>(encb, WmuT, b_mu, b_lv, out_mu, out_lv,
                                                              N, 512, 256, 256, 256, 256, 512 / 128);

    // 6) z -> bf16
    z_kernel<<<(N * 256 / 4 + 255) / 256, 256, 0, stream>>>(out_mu, out_lv, epsin, zb, N * 256 / 4);

    // 7) dec dendritic (K=256): A-resident LDS.  nwg = 1024
    dendritic_dec_res<<<8 * (N / 128), 256, 0, stream>>>(zb, WddecT, bd_dec, decb, N, 512, 20, 8);

    // 8) fused wavedec-dec -> cdec
    wavedec_dec<<<N / 4, 256, 0, stream>>>(decb, cdec);

    // 9) recon = cdec @ BcdT^T [16384,768], K=544.  nwg = 768
    gemm_mfma<0><<<(768 / 128) * (N / 128), 256, 0, stream>>>(cdec, BcdT, nullptr, nullptr, out_recon, nullptr,
                                                              N, 768, 544, 544, 544, 768, 768 / 128);

    (void)ws_size; (void)out_size; (void)n_in;
}

// Round 17
// 392.507 us; speedup vs baseline: 1.2467x; 1.1650x over previous
//
#include <hip/hip_runtime.h>

typedef __attribute__((ext_vector_type(8))) short short8v;
typedef __attribute__((ext_vector_type(8))) unsigned short ushort8v;
typedef __attribute__((ext_vector_type(4))) float float4v;

__device__ __constant__ float c_LO[8] = {
    -0.010597401784997278f, 0.032883011666982945f, 0.030841381835986965f,
    -0.18703481171888114f, -0.02798376941698385f, 0.6308807679295904f,
    0.7148465705525415f, 0.23037781330885523f};
__device__ __constant__ float c_HI[8] = {
    -0.23037781330885523f, 0.7148465705525415f, -0.6308807679295904f,
    -0.02798376941698385f, 0.18703481171888114f, 0.030841381835986965f,
    -0.032883011666982945f, -0.010597401784997278f};

__device__ __forceinline__ unsigned short f2bf(float f) {
    unsigned u = __builtin_bit_cast(unsigned, f);
    unsigned r = u + 0x7fffu + ((u >> 16) & 1u);
    return (unsigned short)(r >> 16);
}
__device__ __forceinline__ float bf2f(unsigned short u) {
    return __builtin_bit_cast(float, (unsigned)u << 16);
}

__device__ __forceinline__ float gelu_fast(float x) {
    float x3 = x * x * x;
    float y = fmaf(0.044715f, x3, x) * 0.7978845608028654f;
    float t = fminf(fmaxf(y * 2.8853900817779268f, -30.f), 30.f);
    float e = exp2f(t);
    return x * e * __builtin_amdgcn_rcpf(e + 1.0f);
}

__device__ __forceinline__ void gload_lds16(const void* g, void* l) {
    __builtin_amdgcn_global_load_lds(g, l, 16, 0, 0);
}

// ---- one DWT level helpers (pywt symmetric) ----
__device__ __forceinline__ void dwt_lvl(const float* __restrict__ in, int n, float* __restrict__ outA,
                                        unsigned short* __restrict__ outD, int m, int lane) {
    for (int j = lane; j < m; j += 64) {
        float a = 0.f, d = 0.f;
#pragma unroll
        for (int i = 0; i < 8; ++i) {
            int p = 2 * j + 7 - i;
            int q = (p < 6) ? (5 - p) : ((p < n + 6) ? (p - 6) : (2 * n + 5 - p));
            float xv = in[q];
            a = fmaf(c_LO[i], xv, a);
            d = fmaf(c_HI[i], xv, d);
        }
        outA[j] = a;
        outD[j] = f2bf(d);
    }
}
__device__ __forceinline__ void dwt_lvl_final(const float* __restrict__ in, int n, unsigned short* __restrict__ outA,
                                              unsigned short* __restrict__ outD, int m, int lane) {
    for (int j = lane; j < m; j += 64) {
        float a = 0.f, d = 0.f;
#pragma unroll
        for (int i = 0; i < 8; ++i) {
            int p = 2 * j + 7 - i;
            int q = (p < 6) ? (5 - p) : ((p < n + 6) ? (p - 6) : (2 * n + 5 - p));
            float xv = in[q];
            a = fmaf(c_LO[i], xv, a);
            d = fmaf(c_HI[i], xv, d);
        }
        outA[j] = f2bf(a);
        outD[j] = f2bf(d);
    }
}

struct Bounds { int b[6]; };

// ---- pack helpers (LDS-tiled transpose, both sides coalesced) ----
__device__ __forceinline__ void job_pack_w(const float* __restrict__ W, unsigned short* __restrict__ WT,
                                           int br, int k0, int n0, int K, int N, int Kpad,
                                           float (*t)[65], int tid) {
#pragma unroll
    for (int i = 0; i < 16; ++i) {
        int idx = tid + i * 256;
        int kk = idx >> 6, nn = idx & 63;
        int k = k0 + kk;
        t[kk][nn] = (k < K) ? W[((size_t)br * K + k) * N + n0 + nn] : 0.f;
    }
    __syncthreads();
#pragma unroll
    for (int i = 0; i < 16; ++i) {
        int idx = tid + i * 256;
        int nn = idx >> 6, kk = idx & 63;
        int k = k0 + kk;
        if (k < Kpad)
            WT[((size_t)br * N + n0 + nn) * Kpad + k] = f2bf(t[kk][nn]);
    }
}

__device__ __forceinline__ void job_pack_basis(const float* __restrict__ basis, unsigned short* __restrict__ BT,
                                               Bounds bd, int brows, int N, int K, int Kpad,
                                               int k0, int n0, float (*t)[65], int tid) {
#pragma unroll
    for (int i = 0; i < 16; ++i) {
        int idx = tid + i * 256;
        int kk = idx >> 6, nn = idx & 63;
        int k = k0 + kk;
        float v = 0.f;
        if (k < K) {
            int s = 0;
#pragma unroll
            for (int u = 1; u < 5; ++u)
                if (k >= bd.b[u]) s = u;
            int lr = k - bd.b[s];
            v = basis[((size_t)s * brows + lr) * N + n0 + nn];
        }
        t[kk][nn] = v;
    }
    __syncthreads();
#pragma unroll
    for (int i = 0; i < 16; ++i) {
        int idx = tid + i * 256;
        int nn = idx >> 6, kk = idx & 63;
        int k = k0 + kk;
        if (k < Kpad)
            BT[(size_t)(n0 + nn) * Kpad + k] = f2bf(t[kk][nn]);
    }
}

// ---- MEGA-PREP: all packs + wavedec(x) + CSR histogram in ONE kernel ----
// ranges: [0,104) basis_enc | [104,212) basis_dec | [212,852) wT_enc | [852,1492) wT_dec
//         [1492,1508) w_mu | [1508,1524) w_lv | [1524,5620) wavedec_x | [5620,6644) hist
__global__ __launch_bounds__(256) void prep_kernel(const float* __restrict__ x,
                                                   const float* __restrict__ basisenc,
                                                   const float* __restrict__ basisdec,
                                                   const float* __restrict__ Wd_enc,
                                                   const float* __restrict__ Wd_dec,
                                                   const float* __restrict__ W_mu,
                                                   const float* __restrict__ W_lv,
                                                   const int* __restrict__ arows, int E,
                                                   unsigned short* __restrict__ cenc,
                                                   unsigned short* __restrict__ BceT,
                                                   unsigned short* __restrict__ BcdT,
                                                   unsigned short* __restrict__ WdencT,
                                                   unsigned short* __restrict__ WddecT,
                                                   unsigned short* __restrict__ WmuT,
                                                   unsigned short* __restrict__ WlvT,
                                                   int* __restrict__ csr_cnt) {
    __shared__ __align__(16) char smem[18688];
    const int bid = blockIdx.x;
    const int tid = threadIdx.x;
    float (*t)[65] = (float(*)[65])smem;

    if (bid < 104) {
        Bounds be = {{0, 54, 108, 210, 407, 794}};
        int b = bid;
        job_pack_basis(basisenc, BceT, be, 768, 512, 794, 800, (b % 13) * 64, (b / 13) * 64, t, tid);
    } else if (bid < 212) {
        Bounds bdd = {{0, 38, 76, 146, 279, 538}};
        int b = bid - 104;
        job_pack_basis(basisdec, BcdT, bdd, 512, 768, 538, 544, (b % 9) * 64, (b / 9) * 64, t, tid);
    } else if (bid < 852) {
        int b = bid - 212;
        int br = b / 32, rem = b % 32;
        job_pack_w(Wd_enc, WdencT, br, (rem % 8) * 64, (rem / 8) * 64, 512, 256, 512, t, tid);
    } else if (bid < 1492) {
        int b = bid - 852;
        int br = b / 32, rem = b % 32;
        job_pack_w(Wd_dec, WddecT, br, (rem % 4) * 64, (rem / 4) * 64, 256, 512, 256, t, tid);
    } else if (bid < 1508) {
        int b = bid - 1492;
        job_pack_w(W_mu, WmuT, 0, (b % 4) * 64, (b / 4) * 64, 256, 256, 256, t, tid);
    } else if (bid < 1524) {
        int b = bid - 1508;
        job_pack_w(W_lv, WlvT, 0, (b % 4) * 64, (b / 4) * 64, 256, 256, 256, t, tid);
    } else if (bid < 5620) {
        // wavedec of x: one wave per row (linearity: h = A · wavekan(x))
        const int widx = tid >> 6, lane = tid & 63;
        const int r = (bid - 1524) * 4 + widx;
        float* b0 = (float*)smem + widx * 1168;  // 768 + 400 per wave
        float* b1 = b0 + 768;
        const float* ip = x + (size_t)r * 768;
        for (int i = lane; i < 768; i += 64) b0[i] = ip[i];
        __syncthreads();
        unsigned short* cr = cenc + (size_t)r * 800;
        dwt_lvl(b0, 768, b1, cr + 407, 387, lane);
        __syncthreads();
        dwt_lvl(b1, 387, b0, cr + 210, 197, lane);
        __syncthreads();
        dwt_lvl(b0, 197, b1, cr + 108, 102, lane);
        __syncthreads();
        dwt_lvl_final(b1, 102, cr + 0, cr + 54, 54, lane);
        if (lane < 6) cr[794 + lane] = 0;
    } else {
        int i = (bid - 5620) * 256 + tid;
        if (i < E) atomicAdd(&csr_cnt[arows[i]], 1);
    }
}

// ---------------- CSR build (scan + scatter) ----------------
__global__ __launch_bounds__(1024) void scan_kernel(const int* __restrict__ cnt, int* __restrict__ offs,
                                                    int* __restrict__ cursor, int Nrows, int E) {
    __shared__ int part[1024];
    int tid = threadIdx.x;
    const int per = Nrows / 1024;  // 16
    int base = tid * per;
    int local[16];
    int s = 0;
    for (int i = 0; i < per; ++i) { local[i] = s; s += cnt[base + i]; }
    part[tid] = s;
    __syncthreads();
    for (int off = 1; off < 1024; off <<= 1) {
        int v = part[tid];
        int w = (tid >= off) ? part[tid - off] : 0;
        __syncthreads();
        part[tid] = v + w;
        __syncthreads();
    }
    int pre = (tid == 0) ? 0 : part[tid - 1];
    for (int i = 0; i < per; ++i) {
        int o = pre + local[i];
        offs[base + i] = o;
        cursor[base + i] = o;
    }
    if (tid == 0) offs[Nrows] = E;
}

__global__ void scatter_kernel(const int* __restrict__ rows, const int* __restrict__ cols,
                               const float* __restrict__ vals, int* __restrict__ cursor,
                               int* __restrict__ ccol, float* __restrict__ cval, int E) {
    int i = blockIdx.x * blockDim.x + threadIdx.x;
    if (i >= E) return;
    int r = rows[i];
    int p = atomicAdd(&cursor[r], 1);
    ccol[p] = cols[i];
    cval[p] = vals[i];
}

// ---- FUSED SpMM gather (512-wide bf16 rows of hx) + LayerNorm -> hbf bf16 ----
// 2-wide software-pipelined gather (two independent row loads in flight).
__global__ __launch_bounds__(256) void spmm_ln(const unsigned short* __restrict__ hx,
                                               const int* __restrict__ offs,
                                               const int* __restrict__ ccol,
                                               const float* __restrict__ cval,
                                               const float* __restrict__ g,
                                               const float* __restrict__ b,
                                               unsigned short* __restrict__ hbf) {
    const int widx = threadIdx.x >> 6, lane = threadIdx.x & 63;
    const int r = blockIdx.x * 4 + widx;
    int s = offs[r], e = offs[r + 1];
    float acc[8] = {}, acc2[8] = {};
    int j = s;
    for (; j + 1 < e; j += 2) {
        int c0 = ccol[j], c1 = ccol[j + 1];
        float v0 = cval[j], v1 = cval[j + 1];
        ushort8v u0 = *(const ushort8v*)(hx + (size_t)c0 * 512 + lane * 8);
        ushort8v u1 = *(const ushort8v*)(hx + (size_t)c1 * 512 + lane * 8);
#pragma unroll
        for (int t = 0; t < 8; ++t) {
            acc[t] = fmaf(v0, bf2f(u0[t]), acc[t]);
            acc2[t] = fmaf(v1, bf2f(u1[t]), acc2[t]);
        }
    }
    if (j < e) {
        int c0 = ccol[j];
        float v0 = cval[j];
        ushort8v u0 = *(const ushort8v*)(hx + (size_t)c0 * 512 + lane * 8);
#pragma unroll
        for (int t = 0; t < 8; ++t) acc[t] = fmaf(v0, bf2f(u0[t]), acc[t]);
    }
#pragma unroll
    for (int t = 0; t < 8; ++t) acc[t] += acc2[t];

    float s1 = 0.f, s2 = 0.f;
#pragma unroll
    for (int t = 0; t < 8; ++t) { s1 += acc[t]; s2 = fmaf(acc[t], acc[t], s2); }
#pragma unroll
    for (int off = 32; off >= 1; off >>= 1) {
        s1 += __shfl_xor(s1, off);
        s2 += __shfl_xor(s2, off);
    }
    float mean = s1 * (1.f / 512.f);
    float var = s2 * (1.f / 512.f) - mean * mean;
    float inv = rsqrtf(var + 1e-5f);
    ushort8v o;
#pragma unroll
    for (int t = 0; t < 8; ++t) {
        int col = lane * 8 + t;
        o[t] = f2bf((acc[t] - mean) * inv * g[col] + b[col]);
    }
    *(ushort8v*)(hbf + (size_t)r * 512 + lane * 8) = o;
}

// ---- FUSED: 4-level wavedec of dec (bf16 in) -> cdec bf16 [N,544] ----
__global__ __launch_bounds__(256) void wavedec_dec(const unsigned short* __restrict__ decb,
                                                   unsigned short* __restrict__ cdec) {
    __shared__ float buf0[4][512];
    __shared__ float buf1[4][272];
    const int widx = threadIdx.x >> 6, lane = threadIdx.x & 63;
    const int r = blockIdx.x * 4 + widx;
    float* b0 = buf0[widx];
    float* b1 = buf1[widx];
    const unsigned short* ip = decb + (size_t)r * 512;
    for (int i = lane; i < 512; i += 64) b0[i] = bf2f(ip[i]);
    __syncthreads();
    unsigned short* cr = cdec + (size_t)r * 544;
    dwt_lvl(b0, 512, b1, cr + 279, 259, lane);
    __syncthreads();
    dwt_lvl(b1, 259, b0, cr + 146, 133, lane);
    __syncthreads();
    dwt_lvl(b0, 133, b1, cr + 76, 70, lane);
    __syncthreads();
    dwt_lvl_final(b1, 70, cr + 0, cr + 38, 38, lane);
    if (lane < 6) cr[538 + lane] = 0;
}

// ---------------- bf16 MFMA GEMM, 1D grid + m-major XCD swizzle ----------------
// MODE 0: f32 out. MODE 1: bf16 out. MODE 2: mu/lv split epilogue.
template <int MODE>
__global__ __launch_bounds__(256) void gemm_mfma(const unsigned short* __restrict__ A,
                                                 const unsigned short* __restrict__ BT,
                                                 const float* __restrict__ bias,
                                                 const float* __restrict__ bias2,
                                                 void* __restrict__ Cv, void* __restrict__ Cv2,
                                                 int M, int N, int K, int lda, int ldb, int ldc, int nx) {
    __shared__ __align__(16) unsigned short As[128 * 32];
    __shared__ __align__(16) unsigned short Bs[128 * 32];
    const int tid = threadIdx.x;
    const int wave = tid >> 6, lane = tid & 63;
    const int nwg = gridDim.x;
    const int logical = (blockIdx.x & 7) * (nwg >> 3) + (blockIdx.x >> 3);
    const int mblk = logical / nx, nblk = logical - mblk * nx;
    const int m0 = mblk * 128, n0 = nblk * 128;
    const int wr = wave >> 1, wc = wave & 1;
    const int frow = lane & 15, fq = lane >> 4;

    const int off0 = tid * 16;
    const int r0 = off0 >> 6, c0 = off0 & 63;
    const int r1 = (off0 + 4096) >> 6, c1 = (off0 + 4096) & 63;
    const char* Ab = (const char*)A;
    const char* Bb = (const char*)BT;
    size_t gA0 = (size_t)(m0 + r0) * lda * 2 + c0;
    size_t gA1 = (size_t)(m0 + r1) * lda * 2 + c1;
    size_t gB0 = (size_t)(n0 + r0) * ldb * 2 + c0;
    size_t gB1 = (size_t)(n0 + r1) * ldb * 2 + c1;
    char* lA0 = (char*)As + wave * 1024;
    char* lB0 = (char*)Bs + wave * 1024;

    const int aoff = (wr * 64 + frow) * 32 + fq * 8;
    const int boff = (wc * 64 + frow) * 32 + fq * 8;

    float4v acc[4][4] = {};
    for (int k0 = 0; k0 < K; k0 += 32) {
        size_t kb2 = (size_t)k0 * 2;
        gload_lds16(Ab + gA0 + kb2, lA0);
        gload_lds16(Ab + gA1 + kb2, lA0 + 4096);
        gload_lds16(Bb + gB0 + kb2, lB0);
        gload_lds16(Bb + gB1 + kb2, lB0 + 4096);
        __syncthreads();
        short8v av[4], bv[4];
#pragma unroll
        for (int i = 0; i < 4; ++i) av[i] = *(const short8v*)(As + aoff + i * 512);
#pragma unroll
        for (int i = 0; i < 4; ++i) bv[i] = *(const short8v*)(Bs + boff + i * 512);
#pragma unroll
        for (int mi = 0; mi < 4; ++mi)
#pragma unroll
            for (int ni = 0; ni < 4; ++ni)
                acc[mi][ni] = __builtin_amdgcn_mfma_f32_16x16x32_bf16(av[mi], bv[ni], acc[mi][ni], 0, 0, 0);
        __syncthreads();
    }
#pragma unroll
    for (int ni = 0; ni < 4; ++ni) {
        int col = n0 + wc * 64 + ni * 16 + frow;
#pragma unroll
        for (int mi = 0; mi < 4; ++mi) {
#pragma unroll
            for (int i = 0; i < 4; ++i) {
                int row = m0 + wr * 64 + mi * 16 + fq * 4 + i;
                if (MODE == 0) {
                    ((float*)Cv)[(size_t)row * ldc + col] = acc[mi][ni][i];
                } else if (MODE == 1) {
                    ((unsigned short*)Cv)[(size_t)row * ldc + col] = f2bf(acc[mi][ni][i]);
                } else {
                    bool isMu = col < 256;
                    int coll = col & 255;
                    float bval = isMu ? bias[coll] : bias2[coll];
                    float* dst = (float*)(isMu ? Cv : Cv2);
                    dst[(size_t)row * 256 + coll] = acc[mi][ni][i] + bval;
                }
            }
        }
    }
}

// ---------------- z = mu + eps * exp(0.5*logvar)  -> bf16 ----------------
__global__ void z_kernel(const float* __restrict__ mu, const float* __restrict__ lv,
                         const float* __restrict__ eps, unsigned short* __restrict__ z, int n4) {
    int i = blockIdx.x * blockDim.x + threadIdx.x;
    if (i >= n4) return;
    float4 m = ((const float4*)mu)[i];
    float4 l = ((const float4*)lv)[i];
    float4 e = ((const float4*)eps)[i];
    ushort4 o;
    o.x = f2bf(m.x + e.x * expf(0.5f * l.x));
    o.y = f2bf(m.y + e.y * expf(0.5f * l.y));
    o.z = f2bf(m.z + e.z * expf(0.5f * l.z));
    o.w = f2bf(m.w + e.w * expf(0.5f * l.w));
    ((ushort4*)z)[i] = o;
}

// ---- dendritic enc (K=512): dual-branch, all 20 branches ----
__global__ __launch_bounds__(256, 2) void dendritic_full(const unsigned short* __restrict__ A,
                                                         const unsigned short* __restrict__ WT,
                                                         const float* __restrict__ bias,
                                                         unsigned short* __restrict__ out,
                                                         int M, int Nc, int K, int nb, int nx) {
    __shared__ __align__(16) unsigned short As[128 * 64];
    __shared__ __align__(16) unsigned short Bs[2][64 * 64];
    const int tid = threadIdx.x;
    const int wave = tid >> 6;
    const int lane = tid & 63;

    const int nwg = gridDim.x;
    const int logical = (blockIdx.x & 7) * (nwg >> 3) + (blockIdx.x >> 3);
    const int mblk = logical / nx;
    const int nblk = logical - mblk * nx;
    const int n0 = nblk * 64, m0 = mblk * 128;

    const int wr = wave >> 1, wc = wave & 1;
    const int frow = lane & 15, fq = lane >> 4;

    int srA[4], scA[4];
#pragma unroll
    for (int i = 0; i < 4; ++i) {
        int ch = i * 256 + tid;
        srA[i] = ch >> 3;
        scA[i] = ((ch & 7) ^ (srA[i] & 7)) * 16;
    }
    int srB[2], scB[2];
#pragma unroll
    for (int i = 0; i < 2; ++i) {
        int ch = i * 256 + tid;
        srB[i] = ch >> 3;
        scB[i] = ((ch & 7) ^ (srB[i] & 7)) * 16;
    }
    const char* Ab = (const char*)A;
    const size_t K2 = (size_t)K * 2;
    const size_t branchBytes = (size_t)Nc * K2;
    char* lA  = (char*)As + wave * 1024;
    char* lB0 = (char*)&Bs[0][0] + wave * 1024;
    char* lB1 = (char*)&Bs[1][0] + wave * 1024;

    float4v hmn[4][2], hmx[4][2];
#pragma unroll
    for (int mi = 0; mi < 4; ++mi)
#pragma unroll
        for (int ni = 0; ni < 2; ++ni) { hmn[mi][ni] = (float4v)(1e30f); hmx[mi][ni] = (float4v)(-1e30f); }

    const int npair = nb >> 1;
    for (int p = 0; p < npair; ++p) {
        const int b0 = 2 * p, b1 = 2 * p + 1;
        const char* Bb0 = (const char*)WT + (size_t)b0 * branchBytes;
        const char* Bb1 = (const char*)WT + (size_t)b1 * branchBytes;
        float4v ac0[4][2], ac1[4][2];
#pragma unroll
        for (int ni = 0; ni < 2; ++ni) {
            int col = n0 + wc * 32 + ni * 16 + frow;
            float bv0 = bias[(size_t)b0 * Nc + col];
            float bv1 = bias[(size_t)b1 * Nc + col];
#pragma unroll
            for (int mi = 0; mi < 4; ++mi) { ac0[mi][ni] = (float4v)(bv0); ac1[mi][ni] = (float4v)(bv1); }
        }
        for (int k0 = 0; k0 < K; k0 += 64) {
            const size_t kby = (size_t)k0 * 2;
#pragma unroll
            for (int i = 0; i < 4; ++i)
                gload_lds16(Ab + (size_t)(m0 + srA[i]) * K2 + kby + scA[i], lA + i * 4096);
#pragma unroll
            for (int i = 0; i < 2; ++i)
                gload_lds16(Bb0 + (size_t)(n0 + srB[i]) * K2 + kby + scB[i], lB0 + i * 4096);
#pragma unroll
            for (int i = 0; i < 2; ++i)
                gload_lds16(Bb1 + (size_t)(n0 + srB[i]) * K2 + kby + scB[i], lB1 + i * 4096);
            __syncthreads();
#pragma unroll
            for (int kk = 0; kk < 2; ++kk) {
                short8v av[4], bv0[2], bv1[2];
                const int slot = kk * 4 + fq;
#pragma unroll
                for (int mi = 0; mi < 4; ++mi) {
                    int ra = wr * 64 + mi * 16 + frow;
                    av[mi] = *(const short8v*)((const char*)As + ra * 128 + ((slot ^ (ra & 7)) * 16));
                }
#pragma unroll
                for (int ni = 0; ni < 2; ++ni) {
                    int rb = wc * 32 + ni * 16 + frow;
                    int rboff = rb * 128 + ((slot ^ (rb & 7)) * 16);
                    bv0[ni] = *(const short8v*)((const char*)&Bs[0][0] + rboff);
                    bv1[ni] = *(const short8v*)((const char*)&Bs[1][0] + rboff);
                }
#pragma unroll
                for (int mi = 0; mi < 4; ++mi)
#pragma unroll
                    for (int ni = 0; ni < 2; ++ni) {
                        ac0[mi][ni] = __builtin_amdgcn_mfma_f32_16x16x32_bf16(av[mi], bv0[ni], ac0[mi][ni], 0, 0, 0);
                        ac1[mi][ni] = __builtin_amdgcn_mfma_f32_16x16x32_bf16(av[mi], bv1[ni], ac1[mi][ni], 0, 0, 0);
                    }
            }
            __syncthreads();
        }
#pragma unroll
        for (int ni = 0; ni < 2; ++ni)
#pragma unroll
            for (int mi = 0; mi < 4; ++mi)
#pragma unroll
                for (int i = 0; i < 4; ++i) {
                    float mn = fminf(ac0[mi][ni][i], ac1[mi][ni][i]);
                    float mx = fmaxf(ac0[mi][ni][i], ac1[mi][ni][i]);
                    hmn[mi][ni][i] = fminf(hmn[mi][ni][i], mn);
                    hmx[mi][ni][i] = fmaxf(hmx[mi][ni][i], mx);
                }
    }

#pragma unroll
    for (int ni = 0; ni < 2; ++ni) {
        int col = n0 + wc * 32 + ni * 16 + frow;
#pragma unroll
        for (int mi = 0; mi < 4; ++mi) {
#pragma unroll
            for (int i = 0; i < 4; ++i) {
                int row = m0 + wr * 64 + mi * 16 + fq * 4 + i;
                float g = fmaxf(gelu_fast(hmn[mi][ni][i]), gelu_fast(hmx[mi][ni][i]));
                out[(size_t)row * Nc + col] = f2bf(g);
            }
        }
    }
}

// ---- dendritic dec (K=256): A-tile RESIDENT in LDS (64 KB), B dual streamed ----
__global__ __launch_bounds__(256, 2) void dendritic_dec_res(const unsigned short* __restrict__ A,
                                                            const unsigned short* __restrict__ WT,
                                                            const float* __restrict__ bias,
                                                            unsigned short* __restrict__ out,
                                                            int M, int Nc, int nb, int nx) {
    constexpr int K = 256;
    __shared__ __align__(16) unsigned short As[128 * 256];
    __shared__ __align__(16) unsigned short Bs[2][64 * 64];
    const int tid = threadIdx.x;
    const int wave = tid >> 6;
    const int lane = tid & 63;

    const int nwg = gridDim.x;
    const int logical = (blockIdx.x & 7) * (nwg >> 3) + (blockIdx.x >> 3);
    const int mblk = logical / nx;
    const int nblk = logical - mblk * nx;
    const int n0 = nblk * 64, m0 = mblk * 128;

    const int wr = wave >> 1, wc = wave & 1;
    const int frow = lane & 15, fq = lane >> 4;

    const char* Ab = (const char*)A;
    const size_t K2 = (size_t)K * 2;
    for (int i = 0; i < 16; ++i) {
        int ch = i * 256 + tid;
        int row = ch >> 5, slot = ch & 31;
        int sslot = (slot & ~7) | ((slot & 7) ^ (row & 7));
        gload_lds16(Ab + (size_t)(m0 + row) * K2 + sslot * 16, (char*)As + i * 4096 + wave * 1024);
    }

    int srB[2], scB[2];
#pragma unroll
    for (int i = 0; i < 2; ++i) {
        int ch = i * 256 + tid;
        srB[i] = ch >> 3;
        scB[i] = ((ch & 7) ^ (srB[i] & 7)) * 16;
    }
    const size_t branchBytes = (size_t)Nc * K2;
    char* lB0 = (char*)&Bs[0][0] + wave * 1024;
    char* lB1 = (char*)&Bs[1][0] + wave * 1024;

    float4v hmn[4][2], hmx[4][2];
#pragma unroll
    for (int mi = 0; mi < 4; ++mi)
#pragma unroll
        for (int ni = 0; ni < 2; ++ni) { hmn[mi][ni] = (float4v)(1e30f); hmx[mi][ni] = (float4v)(-1e30f); }

    const int npair = nb >> 1;
    for (int p = 0; p < npair; ++p) {
        const int b0 = 2 * p, b1 = 2 * p + 1;
        const char* Bb0 = (const char*)WT + (size_t)b0 * branchBytes;
        const char* Bb1 = (const char*)WT + (size_t)b1 * branchBytes;
        float4v ac0[4][2], ac1[4][2];
#pragma unroll
        for (int ni = 0; ni < 2; ++ni) {
            int col = n0 + wc * 32 + ni * 16 + frow;
            float bv0 = bias[(size_t)b0 * Nc + col];
            float bv1 = bias[(size_t)b1 * Nc + col];
#pragma unroll
            for (int mi = 0; mi < 4; ++mi) { ac0[mi][ni] = (float4v)(bv0); ac1[mi][ni] = (float4v)(bv1); }
        }
        for (int k0 = 0; k0 < K; k0 += 64) {
            const size_t kby = (size_t)k0 * 2;
#pragma unroll
            for (int i = 0; i < 2; ++i)
                gload_lds16(Bb0 + (size_t)(n0 + srB[i]) * K2 + kby + scB[i], lB0 + i * 4096);
#pragma unroll
            for (int i = 0; i < 2; ++i)
                gload_lds16(Bb1 + (size_t)(n0 + srB[i]) * K2 + kby + scB[i], lB1 + i * 4096);
            __syncthreads();
#pragma unroll
            for (int kk = 0; kk < 2; ++kk) {
                short8v av[4], bv0[2], bv1[2];
                const int slot = kk * 4 + fq;
#pragma unroll
                for (int mi = 0; mi < 4; ++mi) {
                    int ra = wr * 64 + mi * 16 + frow;
                    int g = (k0 >> 3) + slot;
                    int sl = (g & ~7) | ((g & 7) ^ (ra & 7));
                    av[mi] = *(const short8v*)((const char*)As + ra * 512 + sl * 16);
                }
#pragma unroll
                for (int ni = 0; ni < 2; ++ni) {
                    int rb = wc * 32 + ni * 16 + frow;
                    int rboff = rb * 128 + ((slot ^ (rb & 7)) * 16);
                    bv0[ni] = *(const short8v*)((const char*)&Bs[0][0] + rboff);
                    bv1[ni] = *(const short8v*)((const char*)&Bs[1][0] + rboff);
                }
#pragma unroll
                for (int mi = 0; mi < 4; ++mi)
#pragma unroll
                    for (int ni = 0; ni < 2; ++ni) {
                        ac0[mi][ni] = __builtin_amdgcn_mfma_f32_16x16x32_bf16(av[mi], bv0[ni], ac0[mi][ni], 0, 0, 0);
                        ac1[mi][ni] = __builtin_amdgcn_mfma_f32_16x16x32_bf16(av[mi], bv1[ni], ac1[mi][ni], 0, 0, 0);
                    }
            }
            __syncthreads();
        }
#pragma unroll
        for (int ni = 0; ni < 2; ++ni)
#pragma unroll
            for (int mi = 0; mi < 4; ++mi)
#pragma unroll
                for (int i = 0; i < 4; ++i) {
                    float mn = fminf(ac0[mi][ni][i], ac1[mi][ni][i]);
                    float mx = fmaxf(ac0[mi][ni][i], ac1[mi][ni][i]);
                    hmn[mi][ni][i] = fminf(hmn[mi][ni][i], mn);
                    hmx[mi][ni][i] = fmaxf(hmx[mi][ni][i], mx);
                }
    }

#pragma unroll
    for (int ni = 0; ni < 2; ++ni) {
        int col = n0 + wc * 32 + ni * 16 + frow;
#pragma unroll
        for (int mi = 0; mi < 4; ++mi) {
#pragma unroll
            for (int i = 0; i < 4; ++i) {
                int row = m0 + wr * 64 + mi * 16 + fq * 4 + i;
                float g = fmaxf(gelu_fast(hmn[mi][ni][i]), gelu_fast(hmx[mi][ni][i]));
                out[(size_t)row * Nc + col] = f2bf(g);
            }
        }
    }
}

extern "C" void kernel_launch(void* const* d_in, const int* in_sizes, int n_in,
                              void* d_out, int out_size, void* d_ws, size_t ws_size,
                              hipStream_t stream) {
    const float* x        = (const float*)d_in[0];
    const int*   arows    = (const int*)d_in[1];
    const int*   acols    = (const int*)d_in[2];
    const float* avals    = (const float*)d_in[3];
    const float* basisenc = (const float*)d_in[4];
    const float* ln_g     = (const float*)d_in[5];
    const float* ln_b     = (const float*)d_in[6];
    const float* Wd_enc   = (const float*)d_in[7];
    const float* bd_enc   = (const float*)d_in[8];
    const float* W_mu     = (const float*)d_in[9];
    const float* b_mu     = (const float*)d_in[10];
    const float* W_lv     = (const float*)d_in[11];
    const float* b_lv     = (const float*)d_in[12];
    const float* Wd_dec   = (const float*)d_in[13];
    const float* bd_dec   = (const float*)d_in[14];
    const float* basisdec = (const float*)d_in[15];
    const float* epsin    = (const float*)d_in[16];

    const int N = 16384;
    const int E = in_sizes[1];

    float* ws = (float*)d_ws;
    const size_t A0 = 0;                               // u16 N*512: hx
    const size_t B0 = A0 + (size_t)N * 768;            // u16 N*800: cenc -> [cdec | zb]
    const size_t C0 = B0 + (size_t)N * 400;            // u16: [hbf | encb] -> decb
    const size_t F0 = C0 + (size_t)N * 387;            // u16 weights
    const size_t G0 = F0 + 3100672;                    // CSR

    unsigned short* hx   = (unsigned short*)(ws + A0);
    unsigned short* cenc = (unsigned short*)(ws + B0);
    unsigned short* cdec = (unsigned short*)(ws + B0);
    unsigned short* zb   = cdec + (size_t)N * 544;
    unsigned short* hbf  = (unsigned short*)(ws + C0);
    unsigned short* encb = hbf + (size_t)N * 512;
    unsigned short* decb = (unsigned short*)(ws + C0);
    unsigned short* wF = (unsigned short*)(ws + F0);
    unsigned short* BceT   = wF;                       // 512*800
    unsigned short* BcdT   = BceT + 512 * 800;         // 768*544
    unsigned short* WdencT = BcdT + 768 * 544;         // 20*256*512
    unsigned short* WddecT = WdencT + 20 * 256 * 512;  // 20*512*256
    unsigned short* WmuT   = WddecT + 20 * 512 * 256;  // 256*256
    unsigned short* WlvT   = WmuT + 256 * 256;         // contiguous -> [512,256]
    int*   csr_cnt  = (int*)(ws + G0);
    int*   csr_offs = csr_cnt + N;
    int*   csr_cur  = csr_offs + N + 1;
    int*   csr_col  = csr_cur + N;
    float* csr_val  = (float*)(csr_col + E);

    float* out_recon = (float*)d_out;
    float* out_mu    = out_recon + (size_t)N * 768;
    float* out_lv    = out_mu + (size_t)N * 256;

    // 0) zero hist counts, then MEGA-PREP (packs + wavedec(x) + hist), then scan+scatter
    hipMemsetAsync(csr_cnt, 0, N * sizeof(int), stream);
    {
        const int nwgPrep = 104 + 108 + 640 + 640 + 16 + 16 + (N / 4) + (E + 255) / 256;  // 6644
        prep_kernel<<<nwgPrep, 256, 0, stream>>>(x, basisenc, basisdec, Wd_enc, Wd_dec, W_mu, W_lv,
                                                 arows, E, cenc, BceT, BcdT, WdencT, WddecT, WmuT, WlvT,
                                                 csr_cnt);
    }
    scan_kernel<<<1, 1024, 0, stream>>>(csr_cnt, csr_offs, csr_cur, N, E);
    scatter_kernel<<<(E + 255) / 256, 256, 0, stream>>>(arows, acols, avals, csr_cur, csr_col, csr_val, E);

    // 1) hx = cenc @ BceT^T  [16384,512] bf16, K=800.  nwg = 512
    gemm_mfma<1><<<(512 / 128) * (N / 128), 256, 0, stream>>>(cenc, BceT, nullptr, nullptr, hx, nullptr,
                                                              N, 512, 800, 800, 800, 512, 512 / 128);

    // 2) fused SpMM gather (512-wide) + LayerNorm -> hbf
    spmm_ln<<<N / 4, 256, 0, stream>>>(hx, csr_offs, csr_col, csr_val, ln_g, ln_b, hbf);

    // 3) enc dendritic (K=512): all 20 branches, dual-branch.  nwg = 512
    dendritic_full<<<4 * (N / 128), 256, 0, stream>>>(hbf, WdencT, bd_enc, encb, N, 256, 512, 20, 4);

    // 4) mu & logvar: single-B GEMM over [WmuT|WlvT] = [512,256], split epilogue.  nwg = 512
    gemm_mfma<2><<<(512 / 128) * (N / 128), 256, 0, stream>>>(encb, WmuT, b_mu, b_lv, out_mu, out_lv,
                                                              N, 512, 256, 256, 256, 256, 512 / 128);

    // 5) z -> bf16
    z_kernel<<<(N * 256 / 4 + 255) / 256, 256, 0, stream>>>(out_mu, out_lv, epsin, zb, N * 256 / 4);

    // 6) dec dendritic (K=256): A-resident LDS.  nwg = 1024
    dendritic_dec_res<<<8 * (N / 128), 256, 0, stream>>>(zb, WddecT, bd_dec, decb, N, 512, 20, 8);

    // 7) fused wavedec-dec -> cdec
    wavedec_dec<<<N / 4, 256, 0, stream>>>(decb, cdec);

    // 8) recon = cdec @ BcdT^T [16384,768], K=544.  nwg = 768
    gemm_mfma<0><<<(768 / 128) * (N / 128), 256, 0, stream>>>(cdec, BcdT, nullptr, nullptr, out_recon, nullptr,
                                                              N, 768, 544, 544, 544, 768, 768 / 128);

    (void)ws_size; (void)out_size; (void)n_in;
}